// Round 7
// baseline (1194.124 us; speedup 1.0000x reference)
//
#include <hip/hip_runtime.h>
#include <hip/hip_fp16.h>

#define N_NODES 1000000
#define N_EDGES 4000000
#define N_GRAPHS 32768
#define BN_EPS 1e-5f
#define NBLK1 3907   // ceil(N_NODES/256)

typedef _Float16 f16;
typedef f16   f16x8 __attribute__((ext_vector_type(8)));
typedef float f32x4 __attribute__((ext_vector_type(4)));
typedef float f32x2 __attribute__((ext_vector_type(2)));

// ---------------------------------------------------------------------------
// Static device-global scratch.
// r21: gather-read features fp8 e4m3 (q1, h2). r22: h3 never materialized
// (fused pooling). r23: layer-1 fully fused. r24: degree-sorted row perm +
// predicated edge batches (divergence + serial-tail fix).
// ---------------------------------------------------------------------------
__device__ __half g_hA[128000000];      // 256 MB: q1 fp8 (first 128 MB)
__device__ __half g_hB[128000000];      // 256 MB: px fp16x8 (16 MB) -> h2 fp8 (128 MB)
__device__ float  g_agg7[8400000];      //  33.6 MB: pooled SUMS + hidden
__device__ float  g_dinv[N_NODES];
__device__ int    g_rowcnt[N_NODES];
__device__ int    g_row_start[N_NODES + 1];
__device__ int    g_csr_src[N_EDGES];
__device__ int    g_part[NBLK1];
__device__ int    g_gstart[N_GRAPHS + 1];
__device__ __align__(16) __half g_wt1[4096];    // W1^T fp16 [n][k], K padded to 32
__device__ __align__(16) __half g_wt2[16384];   // W2^T fp16 [n][k]
__device__ __align__(16) __half g_wt3[16384];   // W3^T fp16 [n][k]

#define HIDDEN_OFF 4259840   // pooled sums = g_agg7[0..4194304); hidden after pad

// ---------------- fp16 helpers ----------------

__device__ __forceinline__ void set8(uint4 raw, float f[8]) {
    __half2 h; float2 a;
    __builtin_memcpy(&h, &raw.x, 4); a = __half22float2(h); f[0] = a.x; f[1] = a.y;
    __builtin_memcpy(&h, &raw.y, 4); a = __half22float2(h); f[2] = a.x; f[3] = a.y;
    __builtin_memcpy(&h, &raw.z, 4); a = __half22float2(h); f[4] = a.x; f[5] = a.y;
    __builtin_memcpy(&h, &raw.w, 4); a = __half22float2(h); f[6] = a.x; f[7] = a.y;
}
__device__ __forceinline__ uint4 pack8(const float f[8]) {
    __half2 h0 = __floats2half2_rn(f[0], f[1]);
    __half2 h1 = __floats2half2_rn(f[2], f[3]);
    __half2 h2 = __floats2half2_rn(f[4], f[5]);
    __half2 h3 = __floats2half2_rn(f[6], f[7]);
    uint4 raw;
    __builtin_memcpy(&raw.x, &h0, 4);
    __builtin_memcpy(&raw.y, &h1, 4);
    __builtin_memcpy(&raw.z, &h2, 4);
    __builtin_memcpy(&raw.w, &h3, 4);
    return raw;
}
__device__ __forceinline__ f32x2 cvt2h(unsigned raw) {
    __half2 h; __builtin_memcpy(&h, &raw, 4);
    float2 a = __half22float2(h);
    f32x2 r; r.x = a.x; r.y = a.y; return r;
}

// ---------------- fp8 e4m3 helpers (vector f32x2 accumulators) ----------------

__device__ __forceinline__ void set8_fp8v(uint2 raw, f32x2 f[4]) {
    f[0] = __builtin_amdgcn_cvt_pk_f32_fp8(raw.x, false);
    f[1] = __builtin_amdgcn_cvt_pk_f32_fp8(raw.x, true);
    f[2] = __builtin_amdgcn_cvt_pk_f32_fp8(raw.y, false);
    f[3] = __builtin_amdgcn_cvt_pk_f32_fp8(raw.y, true);
}
__device__ __forceinline__ void add8_fp8v(uint2 raw, f32x2 f[4]) {
    f[0] += __builtin_amdgcn_cvt_pk_f32_fp8(raw.x, false);   // v_pk_add_f32
    f[1] += __builtin_amdgcn_cvt_pk_f32_fp8(raw.x, true);
    f[2] += __builtin_amdgcn_cvt_pk_f32_fp8(raw.y, false);
    f[3] += __builtin_amdgcn_cvt_pk_f32_fp8(raw.y, true);
}
__device__ __forceinline__ uint4 pack8v(const f32x2 f[4]) {
    __half2 h0 = __floats2half2_rn(f[0].x, f[0].y);
    __half2 h1 = __floats2half2_rn(f[1].x, f[1].y);
    __half2 h2 = __floats2half2_rn(f[2].x, f[2].y);
    __half2 h3 = __floats2half2_rn(f[3].x, f[3].y);
    uint4 raw;
    __builtin_memcpy(&raw.x, &h0, 4);
    __builtin_memcpy(&raw.y, &h1, 4);
    __builtin_memcpy(&raw.z, &h2, 4);
    __builtin_memcpy(&raw.w, &h3, 4);
    return raw;
}
__device__ __forceinline__ uint2 pack8_fp8(const float f[8]) {
    int lo = 0, hi = 0;
    lo = __builtin_amdgcn_cvt_pk_fp8_f32(f[0], f[1], lo, false);
    lo = __builtin_amdgcn_cvt_pk_fp8_f32(f[2], f[3], lo, true);
    hi = __builtin_amdgcn_cvt_pk_fp8_f32(f[4], f[5], hi, false);
    hi = __builtin_amdgcn_cvt_pk_fp8_f32(f[6], f[7], hi, true);
    uint2 r; r.x = (unsigned)lo; r.y = (unsigned)hi; return r;
}

// ---------------- CSR build ----------------

__global__ __launch_bounds__(256) void k_zero_cnt() {
    int i = blockIdx.x * 256 + threadIdx.x;
    if (i < N_NODES) g_rowcnt[i] = 0;
}

__global__ __launch_bounds__(256) void k_hist(const int* __restrict__ dst) {
    int e = blockIdx.x * 256 + threadIdx.x;
    if (e < N_EDGES) atomicAdd(&g_rowcnt[dst[e]], 1);
}

__global__ __launch_bounds__(256) void k_scan1() {
    __shared__ int sh[256];
    int i = blockIdx.x * 256 + threadIdx.x;
    int v = (i < N_NODES) ? g_rowcnt[i] : 0;
    if (i < N_NODES) g_dinv[i] = rsqrtf((float)(1 + v));   // +1 self-loop
    sh[threadIdx.x] = v;
    __syncthreads();
#pragma unroll
    for (int off = 1; off < 256; off <<= 1) {
        int t = (threadIdx.x >= off) ? sh[threadIdx.x - off] : 0;
        __syncthreads();
        sh[threadIdx.x] += t;
        __syncthreads();
    }
    int incl = sh[threadIdx.x];
    if (i < N_NODES) g_row_start[i] = incl - v;
    if (threadIdx.x == 255) g_part[blockIdx.x] = incl;
}

__global__ __launch_bounds__(256) void k_scan2() {
    __shared__ int sh[256];
    int base = threadIdx.x * 16;
    int local[16];
    int s = 0;
#pragma unroll
    for (int k = 0; k < 16; ++k) {
        local[k] = (base + k < NBLK1) ? g_part[base + k] : 0;
        s += local[k];
    }
    sh[threadIdx.x] = s;
    __syncthreads();
#pragma unroll
    for (int off = 1; off < 256; off <<= 1) {
        int t = (threadIdx.x >= off) ? sh[threadIdx.x - off] : 0;
        __syncthreads();
        sh[threadIdx.x] += t;
        __syncthreads();
    }
    int carry = sh[threadIdx.x] - s;
#pragma unroll
    for (int k = 0; k < 16; ++k) {
        if (base + k < NBLK1) {
            int t = local[k];
            g_part[base + k] = carry;
            carry += t;
        }
    }
}

__global__ __launch_bounds__(256) void k_scan3() {
    int i = blockIdx.x * 256 + threadIdx.x;
    if (i < N_NODES) {
        g_row_start[i] += g_part[blockIdx.x];
        g_rowcnt[i] = 0;
    }
    if (i == 0) g_row_start[N_NODES] = N_EDGES;
}

__global__ __launch_bounds__(256) void k_scatter(const int* __restrict__ src,
                                                 const int* __restrict__ dst) {
    int e = blockIdx.x * 256 + threadIdx.x;
    if (e >= N_EDGES) return;
    int d = dst[e];
    int pos = g_row_start[d] + atomicAdd(&g_rowcnt[d], 1);
    g_csr_src[pos] = src[e];
}

// ---------------- weight transposes to fp16 ----------------

__global__ __launch_bounds__(256) void k_wt_both(const float* __restrict__ W2,
                                                 const float* __restrict__ W3) {
    int t = blockIdx.x * 256 + threadIdx.x;   // 0..32767
    int sel = t >> 14, u = t & 16383;
    int n = u & 127, k = u >> 7;
    __half* dst = sel ? g_wt3 : g_wt2;
    const float* W = sel ? W3 : W2;
    dst[n * 128 + k] = __float2half_rn(W[k * 128 + n]);
}

// W1^T fp16 [128][32], rows k>=7 zero (K padded for 16x16x32 MFMA)
__global__ __launch_bounds__(256) void k_wt1(const float* __restrict__ W1) {
    int t = blockIdx.x * 256 + threadIdx.x;   // 0..4095
    int n = t & 127, k = t >> 7;              // k 0..31
    g_wt1[n * 32 + k] = (k < 7) ? __float2half_rn(W1[k * 128 + n]) : __float2half_rn(0.f);
}

// ---------------- layer 1 ----------------

// px[i] = fp16x8 padded row of dinv[i]*x[i] (16 B); ch7 = 0.
__global__ __launch_bounds__(256) void k_p7(const float* __restrict__ x) {
    int i = blockIdx.x * 256 + threadIdx.x;
    if (i >= N_NODES) return;
    float w = g_dinv[i];
    float v[8];
#pragma unroll
    for (int k = 0; k < 7; ++k) v[k] = x[i * 7 + k] * w;
    v[7] = 0.f;
    *(uint4*)(g_hB + (size_t)i * 8) = pack8(v);
}

// zero the pooled-sum accumulator (16.78 MB) before layer-3's atomics
__global__ __launch_bounds__(256) void k_zero_pool() {
    int t = blockIdx.x * 256 + threadIdx.x;          // 0..1048575
    *(float4*)(g_agg7 + (size_t)t * 4) = make_float4(0.f, 0.f, 0.f, 0.f);
}

// ---------------- fused layer-1: gather(px) + MFMA lin1 + BN/ReLU -> q1 fp8
// r24: degree-sorted perm (wave = 16 nodes -> max/mean inflation ~2.3x
// without sort) + predicated edge batches (no serial tails).

__global__ __launch_bounds__(256, 7) void k_l1_fused(const float* __restrict__ b,
                                                     const float* __restrict__ g,
                                                     const float* __restrict__ bt,
                                                     const float* __restrict__ rm,
                                                     const float* __restrict__ rv) {
    const __half* __restrict__ px = g_hB;
    unsigned char* __restrict__ q1 = (unsigned char*)g_hA;

    __shared__ __half As[64][152];          // 19,456 B
    __shared__ int deg_sh[64], rs_sh[64], perm_sh[64];
    __shared__ float dinv_sh[64], dvp_sh[64];
    const int tid = threadIdx.x;
    const int node0 = blockIdx.x * 64;

    if (tid < 64) {
        int node = node0 + tid;
        int rs = g_row_start[node];
        rs_sh[tid] = rs;
        deg_sh[tid] = g_row_start[node + 1] - rs;
        dinv_sh[tid] = g_dinv[node];
    }
    __syncthreads();
    if (tid < 64) {
        int d = deg_sh[tid];
        int r = 0;
        for (int j = 0; j < 64; ++j) {
            int dj = deg_sh[j];
            r += (int)((dj > d) || (dj == d && j < tid));
        }
        perm_sh[r] = tid;                // As row r <- node tid
        dvp_sh[r] = dinv_sh[tid];        // dinv by As row
    }
    __syncthreads();

    // ---- gather: 4 threads/node, degree-sorted rows, predicated batches ----
    {
        const int slot = tid >> 2;          // As row 0..63
        const int q = tid & 3;              // channel pair
        int pidx = perm_sh[slot];
        f32x2 f = cvt2h(*(const unsigned*)(px + (size_t)(node0 + pidx) * 8 + q * 2));
        int e = rs_sh[pidx], e1 = e + deg_sh[pidx];
        for (; e < e1; e += 4) {
            int em = e1 - 1;
            int a1 = min(e + 1, em), a2 = min(e + 2, em), a3 = min(e + 3, em);
            int s0 = g_csr_src[e],  s1 = g_csr_src[a1];
            int s2 = g_csr_src[a2], s3 = g_csr_src[a3];
            unsigned r0 = *(const unsigned*)(px + (size_t)s0 * 8 + q * 2);
            unsigned r1 = *(const unsigned*)(px + (size_t)s1 * 8 + q * 2);
            unsigned r2 = *(const unsigned*)(px + (size_t)s2 * 8 + q * 2);
            unsigned r3 = *(const unsigned*)(px + (size_t)s3 * 8 + q * 2);
            if (e + 1 >= e1) r1 = 0u;       // fp16 0x0000 == 0.0
            if (e + 2 >= e1) r2 = 0u;
            if (e + 3 >= e1) r3 = 0u;
            f += cvt2h(r0); f += cvt2h(r1); f += cvt2h(r2); f += cvt2h(r3);
        }
        __half2 hv = __floats2half2_rn(f.x, f.y);
        unsigned u; __builtin_memcpy(&u, &hv, 4);
        *(unsigned*)(&As[slot][q * 2]) = u;
        uint4 z; z.x = 0; z.y = 0; z.z = 0; z.w = 0;
        *(uint4*)(&As[slot][8 + q * 8]) = z;    // zero K pad halves 8..39
    }

    const int wv = tid >> 6;
    const int lane = tid & 63;
    const int lm = lane & 15;
    const int lq = lane >> 4;

    __syncthreads();

    // ---- MFMA: K=32 (single kb) ----
    f32x4 acc[4][2];
#pragma unroll
    for (int mt = 0; mt < 4; ++mt)
#pragma unroll
        for (int nt = 0; nt < 2; ++nt) acc[mt][nt] = (f32x4){0.f, 0.f, 0.f, 0.f};

    f16x8 bq[2];
#pragma unroll
    for (int nt = 0; nt < 2; ++nt)
        __builtin_memcpy(&bq[nt], g_wt1 + (size_t)(wv * 32 + nt * 16 + lm) * 32 + lq * 8, 16);
#pragma unroll
    for (int mt = 0; mt < 4; ++mt) {
        f16x8 afr;
        __builtin_memcpy(&afr, &As[mt * 16 + lm][lq * 8], 16);
#pragma unroll
        for (int nt = 0; nt < 2; ++nt)
            acc[mt][nt] = __builtin_amdgcn_mfma_f32_16x16x32_f16(afr, bq[nt], acc[mt][nt], 0, 0, 0);
    }

    __syncthreads();   // all As gather reads done before C staging

    // ---- epilogue: BN/ReLU (PRE), stage C fp16 in As ----
#pragma unroll
    for (int nt = 0; nt < 2; ++nt) {
        int c = wv * 32 + nt * 16 + lm;
        float s = g[c] * rsqrtf(rv[c] + BN_EPS);
        float o = fmaf(b[c] - rm[c], s, bt[c]);
#pragma unroll
        for (int mt = 0; mt < 4; ++mt) {
#pragma unroll
            for (int r = 0; r < 4; ++r) {
                int arow = mt * 16 + lq * 4 + r;
                float dv = dvp_sh[arow];
                float y = fmaxf(fmaf(acc[mt][nt][r] * dv, s, o), 0.f) * dv;
                As[arow][c] = __float2half_rn(y);
            }
        }
    }
    __syncthreads();
#pragma unroll
    for (int i = 0; i < 2; ++i) {
        int u = tid + i * 256;                 // 0..511
        int row = u >> 3, cb = (u & 7) * 16;   // 16 cols/thread
        float fa[8], fb[8];
        set8(*(const uint4*)(&As[row][cb]), fa);
        set8(*(const uint4*)(&As[row][cb + 8]), fb);
        uint2 pa = pack8_fp8(fa), pb = pack8_fp8(fb);
        uint4 v; v.x = pa.x; v.y = pa.y; v.z = pb.x; v.w = pb.y;
        *(uint4*)(q1 + (size_t)(node0 + perm_sh[row]) * 128 + cb) = v;
    }
}

// ---------------- fused CSR-gather + MFMA GEMM + BN + ReLU (layers 2,3) ----
// LEDGER:
//  r18 interleaved gather -> reg spills. REVERTED.
//  r19 nt stores -> WRITE x5. REVERTED. r19b bounds(256,8) -> thrash. (256,7).
//  r20 occupancy 55->79%, dur flat (HBM-bound regime then). Lever = bytes.
//  r21 fp8 rows: 374 -> 277 us. r22 fused pooling: 277 -> 237 us.
//  r23 f32x2 pk-add; l1 fused. Regime now: nothing saturated (HBM 19%,
//      VALU 36%, MFMA 5.7%) -> serialization inside gather.
//  r24 THIS: degree-sorted row perm (wave max/mean deg inflation 1.6x -> ~1.1x)
//      + predicated 4-edge batches (serial tails deleted). Summation order
//      per node unchanged -> absmax must stay bit-identical.
// OUTMODE: 1 = fp8 row store (layer 2), 2 = fused pool (layer 3).

template <bool PRE, bool ATOB, int WSEL, int OUTMODE>
__global__ __launch_bounds__(256, 7) void k_agg_gemm(const float* __restrict__ b,
                                                     const float* __restrict__ g,
                                                     const float* __restrict__ bt,
                                                     const float* __restrict__ rm,
                                                     const float* __restrict__ rv,
                                                     const int* __restrict__ batch) {
    const unsigned char* __restrict__ hin8 =
        (const unsigned char*)(ATOB ? g_hA : g_hB);          // fp8 rows, 128 B
    unsigned char* __restrict__ hout8 =
        (unsigned char*)(ATOB ? g_hB : g_hA);                // fp8 rows, 128 B
    const __half* __restrict__ WtG = (WSEL == 0) ? g_wt2 : g_wt3;

    __shared__ __half As[64][152];          // 19,456 B
    __shared__ int bsh[64];
    __shared__ int deg_sh[64], rs_sh[64], perm_sh[64], inv_sh[64];
    __shared__ float dinv_sh[64], dvp_sh[64];
    const int tid = threadIdx.x;
    const int node0 = blockIdx.x * 64;

    if (tid < 64) {
        int node = node0 + tid;
        int rs = g_row_start[node];
        rs_sh[tid] = rs;
        deg_sh[tid] = g_row_start[node + 1] - rs;
        dinv_sh[tid] = g_dinv[node];
        if (OUTMODE == 2) bsh[tid] = batch[node];
    }
    __syncthreads();
    if (tid < 64) {
        int d = deg_sh[tid];
        int r = 0;
        for (int j = 0; j < 64; ++j) {
            int dj = deg_sh[j];
            r += (int)((dj > d) || (dj == d && j < tid));
        }
        perm_sh[r] = tid;                // As row r <- node tid
        inv_sh[tid] = r;                 // node tid -> As row
        dvp_sh[r] = dinv_sh[tid];
    }
    __syncthreads();

    // ---- gather: degree-sorted rows, predicated 4-edge batches ----
    {
        const int slot = tid >> 4;          // 0..15
        const int c0 = (tid & 15) * 8;      // 8 channels = 8 fp8 bytes
#pragma unroll
        for (int pass = 0; pass < 4; ++pass) {
            int prow = pass * 16 + slot;    // As row
            int pidx = perm_sh[prow];       // node index within block
            f32x2 f[4];
            set8_fp8v(*(const uint2*)(hin8 + (size_t)(node0 + pidx) * 128 + c0), f);
            int e = rs_sh[pidx], e1 = e + deg_sh[pidx];
            for (; e < e1; e += 4) {
                int em = e1 - 1;
                int a1 = min(e + 1, em), a2 = min(e + 2, em), a3 = min(e + 3, em);
                int s0 = g_csr_src[e],  s1 = g_csr_src[a1];
                int s2 = g_csr_src[a2], s3 = g_csr_src[a3];
                uint2 r0 = *(const uint2*)(hin8 + (size_t)s0 * 128 + c0);
                uint2 r1 = *(const uint2*)(hin8 + (size_t)s1 * 128 + c0);
                uint2 r2 = *(const uint2*)(hin8 + (size_t)s2 * 128 + c0);
                uint2 r3 = *(const uint2*)(hin8 + (size_t)s3 * 128 + c0);
                if (e + 1 >= e1) { r1.x = 0u; r1.y = 0u; }   // fp8 0x00 == 0.0
                if (e + 2 >= e1) { r2.x = 0u; r2.y = 0u; }
                if (e + 3 >= e1) { r3.x = 0u; r3.y = 0u; }
                add8_fp8v(r0, f); add8_fp8v(r1, f); add8_fp8v(r2, f); add8_fp8v(r3, f);
            }
            *(uint4*)(&As[prow][c0]) = pack8v(f);
        }
    }

    const int wv = tid >> 6;        // wave 0..3 -> cols [wv*32, wv*32+32)
    const int lane = tid & 63;
    const int lm = lane & 15;
    const int lq = lane >> 4;

    __syncthreads();

    // ---- MFMA: kb-outer so only 2 B-frags live at a time ----
    f32x4 acc[4][2];
#pragma unroll
    for (int mt = 0; mt < 4; ++mt)
#pragma unroll
        for (int nt = 0; nt < 2; ++nt) acc[mt][nt] = (f32x4){0.f, 0.f, 0.f, 0.f};

#pragma unroll
    for (int kb = 0; kb < 4; ++kb) {
        f16x8 bq[2];
#pragma unroll
        for (int nt = 0; nt < 2; ++nt)
            __builtin_memcpy(&bq[nt],
                             WtG + (size_t)(wv * 32 + nt * 16 + lm) * 128 + kb * 32 + lq * 8, 16);
#pragma unroll
        for (int mt = 0; mt < 4; ++mt) {
            f16x8 afr;
            __builtin_memcpy(&afr, &As[mt * 16 + lm][kb * 32 + lq * 8], 16);
#pragma unroll
            for (int nt = 0; nt < 2; ++nt)
                acc[mt][nt] = __builtin_amdgcn_mfma_f32_16x16x32_f16(afr, bq[nt], acc[mt][nt], 0, 0, 0);
        }
    }

    __syncthreads();

    // ---- epilogue: BN/ReLU, stage C (fp16) in As ----
#pragma unroll
    for (int nt = 0; nt < 2; ++nt) {
        int c = wv * 32 + nt * 16 + lm;
        float s = g[c] * rsqrtf(rv[c] + BN_EPS);
        float o = fmaf(b[c] - rm[c], s, bt[c]);
#pragma unroll
        for (int mt = 0; mt < 4; ++mt) {
#pragma unroll
            for (int r = 0; r < 4; ++r) {
                int arow = mt * 16 + lq * 4 + r;
                float dv = dvp_sh[arow];
                float pm = PRE ? dv : 1.0f;
                float y = fmaxf(fmaf(acc[mt][nt][r] * dv, s, o), 0.f) * pm;
                As[arow][c] = __float2half_rn(y);
            }
        }
    }
    __syncthreads();

    if (OUTMODE == 1) {
#pragma unroll
        for (int i = 0; i < 2; ++i) {
            int u = tid + i * 256;                 // 0..511
            int row = u >> 3, cb = (u & 7) * 16;   // 16 cols/thread
            float fa[8], fb[8];
            set8(*(const uint4*)(&As[row][cb]), fa);
            set8(*(const uint4*)(&As[row][cb + 8]), fb);
            uint2 pa = pack8_fp8(fa), pb = pack8_fp8(fb);
            uint4 v; v.x = pa.x; v.y = pa.y; v.z = pb.x; v.w = pb.y;
            *(uint4*)(hout8 + (size_t)(node0 + perm_sh[row]) * 128 + cb) = v;
        }
    } else {
        // fused segment-sum pooling: iterate ORIGINAL node order (batch
        // sorted -> runs preserved); read staged C via inv_sh.
        const int c = tid & 127;
        const int r0 = (tid >> 7) * 32;
        float accp = 0.f;
        int g0 = bsh[r0];
        for (int orig = r0; orig < r0 + 32; ++orig) {
            int gg = bsh[orig];
            if (gg != g0) {
                atomicAdd(&g_agg7[(size_t)g0 * 128 + c], accp);
                accp = 0.f; g0 = gg;
            }
            accp += __half2float(As[inv_sh[orig]][c]);
        }
        atomicAdd(&g_agg7[(size_t)g0 * 128 + c], accp);
    }
}

// ---------------- pooling boundaries + head ----------------

__global__ __launch_bounds__(256) void k_gstart(const int* __restrict__ batch) {
    int gidx = blockIdx.x * 256 + threadIdx.x;
    if (gidx > N_GRAPHS) return;
    int lo = 0, hi = N_NODES;
    while (lo < hi) {
        int mid = (lo + hi) >> 1;
        if (batch[mid] < gidx) lo = mid + 1; else hi = mid;
    }
    g_gstart[gidx] = lo;
}

// hidden = relu((pooled_sum/cnt) @ Wc1 + bc1)
__global__ __launch_bounds__(256) void k_head1(const float* __restrict__ Wc1,
                                               const float* __restrict__ bc1) {
    int t = blockIdx.x * 256 + threadIdx.x;
    int gi = t >> 6, c = t & 63;
    if (gi >= N_GRAPHS) return;
    const float* pooled = g_agg7;
    float* hidden = g_agg7 + HIDDEN_OFF;
    int cnt = g_gstart[gi + 1] - g_gstart[gi];
    float inv = 1.0f / (float)max(cnt, 1);
    float z = 0.f;
#pragma unroll 8
    for (int k = 0; k < 128; ++k) z = fmaf(pooled[gi * 128 + k], Wc1[k * 64 + c], z);
    hidden[t] = fmaxf(fmaf(z, inv, bc1[c]), 0.f);
}

__global__ __launch_bounds__(256) void k_head2(const float* __restrict__ Wc2,
                                               const float* __restrict__ bc2,
                                               float* __restrict__ out) {
    int gi = blockIdx.x * 256 + threadIdx.x;
    if (gi >= N_GRAPHS) return;
    const float* hidden = g_agg7 + HIDDEN_OFF;
    float z = bc2[0];
#pragma unroll 8
    for (int k = 0; k < 64; ++k) z = fmaf(hidden[gi * 64 + k], Wc2[k], z);
    out[gi] = z;
}

// ---------------- launch ----------------

extern "C" void kernel_launch(void* const* d_in, const int* in_sizes, int n_in,
                              void* d_out, int out_size, void* d_ws, size_t ws_size,
                              hipStream_t stream) {
    const float* x     = (const float*)d_in[0];
    const int*   ei    = (const int*)d_in[1];
    const int*   batch = (const int*)d_in[2];
    const float* W1 = (const float*)d_in[3];
    const float* b1 = (const float*)d_in[4];
    const float* g1 = (const float*)d_in[5];
    const float* bt1= (const float*)d_in[6];
    const float* rm1= (const float*)d_in[7];
    const float* rv1= (const float*)d_in[8];
    const float* W2 = (const float*)d_in[9];
    const float* b2 = (const float*)d_in[10];
    const float* g2 = (const float*)d_in[11];
    const float* bt2= (const float*)d_in[12];
    const float* rm2= (const float*)d_in[13];
    const float* rv2= (const float*)d_in[14];
    const float* W3 = (const float*)d_in[15];
    const float* b3 = (const float*)d_in[16];
    const float* g3 = (const float*)d_in[17];
    const float* bt3= (const float*)d_in[18];
    const float* rm3= (const float*)d_in[19];
    const float* rv3= (const float*)d_in[20];
    const float* Wc1= (const float*)d_in[21];
    const float* bc1= (const float*)d_in[22];
    const float* Wc2= (const float*)d_in[23];
    const float* bc2= (const float*)d_in[24];
    float* outp = (float*)d_out;
    (void)d_ws; (void)ws_size; (void)n_in; (void)in_sizes;

    const int* srcp = ei;
    const int* dstp = ei + N_EDGES;

    // CSR build (by dst) + dinv (fused into scan1)
    k_zero_cnt<<<NBLK1, 256, 0, stream>>>();
    k_hist<<<(N_EDGES + 255) / 256, 256, 0, stream>>>(dstp);
    k_scan1<<<NBLK1, 256, 0, stream>>>();
    k_scan2<<<1, 256, 0, stream>>>();
    k_scan3<<<NBLK1, 256, 0, stream>>>();
    k_scatter<<<(N_EDGES + 255) / 256, 256, 0, stream>>>(srcp, dstp);

    // weight transposes -> fp16
    k_wt_both<<<128, 256, 0, stream>>>(W2, W3);
    k_wt1<<<16, 256, 0, stream>>>(W1);

    // graph boundaries + pooled-sum zeroing
    k_gstart<<<(N_GRAPHS + 1 + 255) / 256, 256, 0, stream>>>(batch);
    k_zero_pool<<<4096, 256, 0, stream>>>();

    // layer 1: px fp16x8 -> fused gather+MFMA lin1+BN/ReLU -> q1 fp8
    k_p7<<<(N_NODES + 255) / 256, 256, 0, stream>>>(x);
    k_l1_fused<<<N_NODES / 64, 256, 0, stream>>>(b1, g1, bt1, rm1, rv1);

    // layers 2,3: fused gather + MFMA GEMM
    k_agg_gemm<true,  true,  0, 1><<<N_NODES / 64, 256, 0, stream>>>(b2, g2, bt2, rm2, rv2, batch);
    k_agg_gemm<false, false, 1, 2><<<N_NODES / 64, 256, 0, stream>>>(b3, g3, bt3, rm3, rv3, batch);

    // head MLP
    k_head1<<<(N_GRAPHS * 64) / 256, 256, 0, stream>>>(Wc1, bc1);
    k_head2<<<(N_GRAPHS + 255) / 256, 256, 0, stream>>>(Wc2, bc2, outp);
}

// Round 8
// 1109.944 us; speedup vs baseline: 1.0758x; 1.0758x over previous
//
#include <hip/hip_runtime.h>
#include <hip/hip_fp16.h>

#define N_NODES 1000000
#define N_EDGES 4000000
#define N_GRAPHS 32768
#define BN_EPS 1e-5f
#define NBLK1 3907   // ceil(N_NODES/256)

typedef _Float16 f16;
typedef f16   f16x8 __attribute__((ext_vector_type(8)));
typedef float f32x4 __attribute__((ext_vector_type(4)));
typedef float f32x2 __attribute__((ext_vector_type(2)));

// ---------------------------------------------------------------------------
// Static device-global scratch.
// r21: gather-read features fp8 e4m3 (q1, h2). r22: h3 never materialized
// (fused pooling). r23: layer-1 fully fused. r24 degree-sort REGRESSED
// (FETCH 320->603 MB, L3 hit halved) -> REVERTED to r23 gather. r25:
// launch consolidation (prep/gz/head fusions, px into scan1).
// ---------------------------------------------------------------------------
__device__ __half g_hA[128000000];      // 256 MB: q1 fp8 (first 128 MB)
__device__ __half g_hB[128000000];      // 256 MB: px fp16x8 (16 MB) -> h2 fp8 (128 MB)
__device__ float  g_agg7[8400000];      //  33.6 MB: pooled SUMS
__device__ float  g_dinv[N_NODES];
__device__ int    g_rowcnt[N_NODES];
__device__ int    g_row_start[N_NODES + 1];
__device__ int    g_csr_src[N_EDGES];
__device__ int    g_part[NBLK1];
__device__ int    g_gstart[N_GRAPHS + 1];
__device__ __align__(16) __half g_wt1[4096];    // W1^T fp16 [n][k], K padded to 32
__device__ __align__(16) __half g_wt2[16384];   // W2^T fp16 [n][k]
__device__ __align__(16) __half g_wt3[16384];   // W3^T fp16 [n][k]

// ---------------- fp16 helpers ----------------

__device__ __forceinline__ void set8(uint4 raw, float f[8]) {
    __half2 h; float2 a;
    __builtin_memcpy(&h, &raw.x, 4); a = __half22float2(h); f[0] = a.x; f[1] = a.y;
    __builtin_memcpy(&h, &raw.y, 4); a = __half22float2(h); f[2] = a.x; f[3] = a.y;
    __builtin_memcpy(&h, &raw.z, 4); a = __half22float2(h); f[4] = a.x; f[5] = a.y;
    __builtin_memcpy(&h, &raw.w, 4); a = __half22float2(h); f[6] = a.x; f[7] = a.y;
}
__device__ __forceinline__ uint4 pack8(const float f[8]) {
    __half2 h0 = __floats2half2_rn(f[0], f[1]);
    __half2 h1 = __floats2half2_rn(f[2], f[3]);
    __half2 h2 = __floats2half2_rn(f[4], f[5]);
    __half2 h3 = __floats2half2_rn(f[6], f[7]);
    uint4 raw;
    __builtin_memcpy(&raw.x, &h0, 4);
    __builtin_memcpy(&raw.y, &h1, 4);
    __builtin_memcpy(&raw.z, &h2, 4);
    __builtin_memcpy(&raw.w, &h3, 4);
    return raw;
}
__device__ __forceinline__ f32x2 cvt2h(unsigned raw) {
    __half2 h; __builtin_memcpy(&h, &raw, 4);
    float2 a = __half22float2(h);
    f32x2 r; r.x = a.x; r.y = a.y; return r;
}

// ---------------- fp8 e4m3 helpers (vector f32x2 accumulators) ----------------

__device__ __forceinline__ void set8_fp8v(uint2 raw, f32x2 f[4]) {
    f[0] = __builtin_amdgcn_cvt_pk_f32_fp8(raw.x, false);
    f[1] = __builtin_amdgcn_cvt_pk_f32_fp8(raw.x, true);
    f[2] = __builtin_amdgcn_cvt_pk_f32_fp8(raw.y, false);
    f[3] = __builtin_amdgcn_cvt_pk_f32_fp8(raw.y, true);
}
__device__ __forceinline__ void add8_fp8v(uint2 raw, f32x2 f[4]) {
    f[0] += __builtin_amdgcn_cvt_pk_f32_fp8(raw.x, false);   // v_pk_add_f32
    f[1] += __builtin_amdgcn_cvt_pk_f32_fp8(raw.x, true);
    f[2] += __builtin_amdgcn_cvt_pk_f32_fp8(raw.y, false);
    f[3] += __builtin_amdgcn_cvt_pk_f32_fp8(raw.y, true);
}
__device__ __forceinline__ uint4 pack8v(const f32x2 f[4]) {
    __half2 h0 = __floats2half2_rn(f[0].x, f[0].y);
    __half2 h1 = __floats2half2_rn(f[1].x, f[1].y);
    __half2 h2 = __floats2half2_rn(f[2].x, f[2].y);
    __half2 h3 = __floats2half2_rn(f[3].x, f[3].y);
    uint4 raw;
    __builtin_memcpy(&raw.x, &h0, 4);
    __builtin_memcpy(&raw.y, &h1, 4);
    __builtin_memcpy(&raw.z, &h2, 4);
    __builtin_memcpy(&raw.w, &h3, 4);
    return raw;
}
__device__ __forceinline__ uint2 pack8_fp8(const float f[8]) {
    int lo = 0, hi = 0;
    lo = __builtin_amdgcn_cvt_pk_fp8_f32(f[0], f[1], lo, false);
    lo = __builtin_amdgcn_cvt_pk_fp8_f32(f[2], f[3], lo, true);
    hi = __builtin_amdgcn_cvt_pk_fp8_f32(f[4], f[5], hi, false);
    hi = __builtin_amdgcn_cvt_pk_fp8_f32(f[6], f[7], hi, true);
    uint2 r; r.x = (unsigned)lo; r.y = (unsigned)hi; return r;
}

// ---------------- prep: zero rowcnt + all weight transposes (1 launch) ----

__global__ __launch_bounds__(256) void k_prep(const float* __restrict__ W1,
                                              const float* __restrict__ W2,
                                              const float* __restrict__ W3) {
    int t = blockIdx.x * 256 + threadIdx.x;
    if (t < N_NODES) { g_rowcnt[t] = 0; return; }
    int u = t - N_NODES;
    if (u < 32768) {                       // W2/W3 -> fp16 transposed
        int sel = u >> 14, v = u & 16383;
        int n = v & 127, k = v >> 7;
        (sel ? g_wt3 : g_wt2)[n * 128 + k] = __float2half_rn((sel ? W3 : W2)[k * 128 + n]);
        return;
    }
    u -= 32768;
    if (u < 4096) {                        // W1^T fp16 [128][32], k>=7 zero
        int n = u & 127, k = u >> 7;
        g_wt1[n * 32 + k] = (k < 7) ? __float2half_rn(W1[k * 128 + n]) : __float2half_rn(0.f);
    }
}

// ---------------- CSR build ----------------

__global__ __launch_bounds__(256) void k_hist(const int* __restrict__ dst) {
    int e = blockIdx.x * 256 + threadIdx.x;
    if (e < N_EDGES) atomicAdd(&g_rowcnt[dst[e]], 1);
}

// scan1 also computes dinv AND px (fp16x8 row of dinv*x) — r25 fusion
__global__ __launch_bounds__(256) void k_scan1(const float* __restrict__ x) {
    __shared__ int sh[256];
    int i = blockIdx.x * 256 + threadIdx.x;
    int v = (i < N_NODES) ? g_rowcnt[i] : 0;
    if (i < N_NODES) {
        float w = rsqrtf((float)(1 + v));   // +1 self-loop
        g_dinv[i] = w;
        float vv[8];
#pragma unroll
        for (int k = 0; k < 7; ++k) vv[k] = x[i * 7 + k] * w;
        vv[7] = 0.f;
        *(uint4*)(g_hB + (size_t)i * 8) = pack8(vv);
    }
    sh[threadIdx.x] = v;
    __syncthreads();
#pragma unroll
    for (int off = 1; off < 256; off <<= 1) {
        int t = (threadIdx.x >= off) ? sh[threadIdx.x - off] : 0;
        __syncthreads();
        sh[threadIdx.x] += t;
        __syncthreads();
    }
    int incl = sh[threadIdx.x];
    if (i < N_NODES) g_row_start[i] = incl - v;
    if (threadIdx.x == 255) g_part[blockIdx.x] = incl;
}

__global__ __launch_bounds__(256) void k_scan2() {
    __shared__ int sh[256];
    int base = threadIdx.x * 16;
    int local[16];
    int s = 0;
#pragma unroll
    for (int k = 0; k < 16; ++k) {
        local[k] = (base + k < NBLK1) ? g_part[base + k] : 0;
        s += local[k];
    }
    sh[threadIdx.x] = s;
    __syncthreads();
#pragma unroll
    for (int off = 1; off < 256; off <<= 1) {
        int t = (threadIdx.x >= off) ? sh[threadIdx.x - off] : 0;
        __syncthreads();
        sh[threadIdx.x] += t;
        __syncthreads();
    }
    int carry = sh[threadIdx.x] - s;
#pragma unroll
    for (int k = 0; k < 16; ++k) {
        if (base + k < NBLK1) {
            int t = local[k];
            g_part[base + k] = carry;
            carry += t;
        }
    }
}

__global__ __launch_bounds__(256) void k_scan3() {
    int i = blockIdx.x * 256 + threadIdx.x;
    if (i < N_NODES) {
        g_row_start[i] += g_part[blockIdx.x];
        g_rowcnt[i] = 0;
    }
    if (i == 0) g_row_start[N_NODES] = N_EDGES;
}

__global__ __launch_bounds__(256) void k_scatter(const int* __restrict__ src,
                                                 const int* __restrict__ dst) {
    int e = blockIdx.x * 256 + threadIdx.x;
    if (e >= N_EDGES) return;
    int d = dst[e];
    int pos = g_row_start[d] + atomicAdd(&g_rowcnt[d], 1);
    g_csr_src[pos] = src[e];
}

// ---------------- gstart + pooled zero (1 launch) ----------------

__global__ __launch_bounds__(256) void k_gz(const int* __restrict__ batch) {
    int blk = blockIdx.x;
    if (blk < 4096) {                      // zero pooled sums (16.78 MB)
        int t = blk * 256 + threadIdx.x;
        *(float4*)(g_agg7 + (size_t)t * 4) = make_float4(0.f, 0.f, 0.f, 0.f);
        return;
    }
    int gidx = (blk - 4096) * 256 + threadIdx.x;
    if (gidx > N_GRAPHS) return;
    int lo = 0, hi = N_NODES;
    while (lo < hi) {
        int mid = (lo + hi) >> 1;
        if (batch[mid] < gidx) lo = mid + 1; else hi = mid;
    }
    g_gstart[gidx] = lo;
}

// ---------------- fused layer-1: gather(px) + MFMA lin1 + BN/ReLU -> q1 fp8

__global__ __launch_bounds__(256, 7) void k_l1_fused(const float* __restrict__ b,
                                                     const float* __restrict__ g,
                                                     const float* __restrict__ bt,
                                                     const float* __restrict__ rm,
                                                     const float* __restrict__ rv) {
    const __half* __restrict__ px = g_hB;
    unsigned char* __restrict__ q1 = (unsigned char*)g_hA;

    __shared__ __half As[64][152];          // 19,456 B
    const int tid = threadIdx.x;
    const int node0 = blockIdx.x * 64;

    // ---- gather: 4 threads/node, one pass ----
    {
        const int slot = tid >> 2;          // 0..63
        const int q = tid & 3;              // channel pair
        int i = node0 + slot;
        f32x2 f = cvt2h(*(const unsigned*)(px + (size_t)i * 8 + q * 2));   // self
        int e = g_row_start[i], e1 = g_row_start[i + 1];
        for (; e + 4 <= e1; e += 4) {
            int s0 = g_csr_src[e + 0], s1 = g_csr_src[e + 1];
            int s2 = g_csr_src[e + 2], s3 = g_csr_src[e + 3];
            unsigned r0 = *(const unsigned*)(px + (size_t)s0 * 8 + q * 2);
            unsigned r1 = *(const unsigned*)(px + (size_t)s1 * 8 + q * 2);
            unsigned r2 = *(const unsigned*)(px + (size_t)s2 * 8 + q * 2);
            unsigned r3 = *(const unsigned*)(px + (size_t)s3 * 8 + q * 2);
            f += cvt2h(r0); f += cvt2h(r1); f += cvt2h(r2); f += cvt2h(r3);
        }
        for (; e < e1; ++e)
            f += cvt2h(*(const unsigned*)(px + (size_t)g_csr_src[e] * 8 + q * 2));
        __half2 hv = __floats2half2_rn(f.x, f.y);
        unsigned u; __builtin_memcpy(&u, &hv, 4);
        *(unsigned*)(&As[slot][q * 2]) = u;
        uint4 z; z.x = 0; z.y = 0; z.z = 0; z.w = 0;
        *(uint4*)(&As[slot][8 + q * 8]) = z;    // zero K pad halves 8..39
    }

    const int wv = tid >> 6;        // wave 0..3 -> cols [wv*32, wv*32+32)
    const int lane = tid & 63;
    const int lm = lane & 15;
    const int lq = lane >> 4;

    __syncthreads();

    // ---- MFMA: K=32 (single kb) ----
    f32x4 acc[4][2];
#pragma unroll
    for (int mt = 0; mt < 4; ++mt)
#pragma unroll
        for (int nt = 0; nt < 2; ++nt) acc[mt][nt] = (f32x4){0.f, 0.f, 0.f, 0.f};

    f16x8 bq[2];
#pragma unroll
    for (int nt = 0; nt < 2; ++nt)
        __builtin_memcpy(&bq[nt], g_wt1 + (size_t)(wv * 32 + nt * 16 + lm) * 32 + lq * 8, 16);
#pragma unroll
    for (int mt = 0; mt < 4; ++mt) {
        f16x8 afr;
        __builtin_memcpy(&afr, &As[mt * 16 + lm][lq * 8], 16);
#pragma unroll
        for (int nt = 0; nt < 2; ++nt)
            acc[mt][nt] = __builtin_amdgcn_mfma_f32_16x16x32_f16(afr, bq[nt], acc[mt][nt], 0, 0, 0);
    }

    float4 dv4[4];
#pragma unroll
    for (int mt = 0; mt < 4; ++mt)
        dv4[mt] = *(const float4*)(g_dinv + node0 + mt * 16 + lq * 4);

    __syncthreads();   // all As gather reads done before C staging

    // ---- epilogue: BN/ReLU (PRE), stage C fp16 in As ----
#pragma unroll
    for (int nt = 0; nt < 2; ++nt) {
        int c = wv * 32 + nt * 16 + lm;
        float s = g[c] * rsqrtf(rv[c] + BN_EPS);
        float o = fmaf(b[c] - rm[c], s, bt[c]);
#pragma unroll
        for (int mt = 0; mt < 4; ++mt) {
            float dvr[4] = {dv4[mt].x, dv4[mt].y, dv4[mt].z, dv4[mt].w};
#pragma unroll
            for (int r = 0; r < 4; ++r) {
                float y = fmaxf(fmaf(acc[mt][nt][r] * dvr[r], s, o), 0.f) * dvr[r];
                As[mt * 16 + lq * 4 + r][c] = __float2half_rn(y);
            }
        }
    }
    __syncthreads();
#pragma unroll
    for (int i = 0; i < 2; ++i) {
        int u = tid + i * 256;                 // 0..511
        int row = u >> 3, cb = (u & 7) * 16;   // 16 cols/thread
        float fa[8], fb[8];
        set8(*(const uint4*)(&As[row][cb]), fa);
        set8(*(const uint4*)(&As[row][cb + 8]), fb);
        uint2 pa = pack8_fp8(fa), pb = pack8_fp8(fb);
        uint4 v; v.x = pa.x; v.y = pa.y; v.z = pb.x; v.w = pb.y;
        *(uint4*)(q1 + (size_t)(node0 + row) * 128 + cb) = v;
    }
}

// ---------------- fused CSR-gather + MFMA GEMM + BN + ReLU (layers 2,3) ----
// LEDGER:
//  r18 interleaved gather -> reg spills. REVERTED.
//  r19 nt stores -> WRITE x5. REVERTED. r19b bounds(256,8) -> spill thrash
//      (VGPR cap 64 < ~68 true arch+acc use). Stay at (256,7).
//  r20 occupancy 55->79%, dur flat. r21 fp8 rows: 374 -> 277 us.
//  r22 fused pooling: 277 -> 237 us. r23 l1 fused, f32x2 pk-add.
//  r24 degree-sort+predication: REGRESSED (236->260 us, FETCH 320->603 MB,
//      L3 hit halved). REVERTED — sequential gather at ~77% occ is near the
//      random-128B-row service floor (~2.7 TB/s effective).
// OUTMODE: 1 = fp8 row store (layer 2), 2 = fused pool (layer 3).

template <bool PRE, bool ATOB, int WSEL, int OUTMODE>
__global__ __launch_bounds__(256, 7) void k_agg_gemm(const float* __restrict__ b,
                                                     const float* __restrict__ g,
                                                     const float* __restrict__ bt,
                                                     const float* __restrict__ rm,
                                                     const float* __restrict__ rv,
                                                     const int* __restrict__ batch) {
    const unsigned char* __restrict__ hin8 =
        (const unsigned char*)(ATOB ? g_hA : g_hB);          // fp8 rows, 128 B
    unsigned char* __restrict__ hout8 =
        (unsigned char*)(ATOB ? g_hB : g_hA);                // fp8 rows, 128 B
    const __half* __restrict__ WtG = (WSEL == 0) ? g_wt2 : g_wt3;

    __shared__ __half As[64][152];          // 19,456 B
    __shared__ int bsh[64];
    const int tid = threadIdx.x;
    const int node0 = blockIdx.x * 64;

    // ---- gather phase (sequential 4-pass; fp8 rows, f32x2 accumulate) ----
    {
        const int slot = tid >> 4;          // 0..15
        const int c0 = (tid & 15) * 8;      // 8 channels = 8 fp8 bytes
#pragma unroll
        for (int pass = 0; pass < 4; ++pass) {
            int i = node0 + pass * 16 + slot;
            f32x2 f[4];
            set8_fp8v(*(const uint2*)(hin8 + (size_t)i * 128 + c0), f);   // self
            int e = g_row_start[i], e1 = g_row_start[i + 1];
            for (; e + 4 <= e1; e += 4) {
                int s0 = g_csr_src[e + 0], s1 = g_csr_src[e + 1];
                int s2 = g_csr_src[e + 2], s3 = g_csr_src[e + 3];
                uint2 r0 = *(const uint2*)(hin8 + (size_t)s0 * 128 + c0);
                uint2 r1 = *(const uint2*)(hin8 + (size_t)s1 * 128 + c0);
                uint2 r2 = *(const uint2*)(hin8 + (size_t)s2 * 128 + c0);
                uint2 r3 = *(const uint2*)(hin8 + (size_t)s3 * 128 + c0);
                add8_fp8v(r0, f); add8_fp8v(r1, f); add8_fp8v(r2, f); add8_fp8v(r3, f);
            }
            for (; e < e1; ++e) {
                int s = g_csr_src[e];
                add8_fp8v(*(const uint2*)(hin8 + (size_t)s * 128 + c0), f);
            }
            int row = pass * 16 + slot;
            *(uint4*)(&As[row][c0]) = pack8v(f);
        }
    }

    const int wv = tid >> 6;        // wave 0..3 -> cols [wv*32, wv*32+32)
    const int lane = tid & 63;
    const int lm = lane & 15;
    const int lq = lane >> 4;

    __syncthreads();

    // ---- MFMA: kb-outer so only 2 B-frags live at a time ----
    f32x4 acc[4][2];
#pragma unroll
    for (int mt = 0; mt < 4; ++mt)
#pragma unroll
        for (int nt = 0; nt < 2; ++nt) acc[mt][nt] = (f32x4){0.f, 0.f, 0.f, 0.f};

#pragma unroll
    for (int kb = 0; kb < 4; ++kb) {
        f16x8 bq[2];
#pragma unroll
        for (int nt = 0; nt < 2; ++nt)
            __builtin_memcpy(&bq[nt],
                             WtG + (size_t)(wv * 32 + nt * 16 + lm) * 128 + kb * 32 + lq * 8, 16);
#pragma unroll
        for (int mt = 0; mt < 4; ++mt) {
            f16x8 afr;
            __builtin_memcpy(&afr, &As[mt * 16 + lm][kb * 32 + lq * 8], 16);
#pragma unroll
            for (int nt = 0; nt < 2; ++nt)
                acc[mt][nt] = __builtin_amdgcn_mfma_f32_16x16x32_f16(afr, bq[nt], acc[mt][nt], 0, 0, 0);
        }
    }

    float4 dv4[4];
#pragma unroll
    for (int mt = 0; mt < 4; ++mt)
        dv4[mt] = *(const float4*)(g_dinv + node0 + mt * 16 + lq * 4);

    if (OUTMODE == 2 && tid < 64) bsh[tid] = batch[node0 + tid];

    __syncthreads();

    // ---- epilogue: BN/ReLU, stage C (fp16) in As ----
#pragma unroll
    for (int nt = 0; nt < 2; ++nt) {
        int c = wv * 32 + nt * 16 + lm;
        float s = g[c] * rsqrtf(rv[c] + BN_EPS);
        float o = fmaf(b[c] - rm[c], s, bt[c]);
#pragma unroll
        for (int mt = 0; mt < 4; ++mt) {
            float dvr[4] = {dv4[mt].x, dv4[mt].y, dv4[mt].z, dv4[mt].w};
#pragma unroll
            for (int r = 0; r < 4; ++r) {
                float pm = PRE ? dvr[r] : 1.0f;
                float y = fmaxf(fmaf(acc[mt][nt][r] * dvr[r], s, o), 0.f) * pm;
                As[mt * 16 + lq * 4 + r][c] = __float2half_rn(y);
            }
        }
    }
    __syncthreads();

    if (OUTMODE == 1) {
#pragma unroll
        for (int i = 0; i < 2; ++i) {
            int u = tid + i * 256;                 // 0..511
            int row = u >> 3, cb = (u & 7) * 16;   // 16 cols/thread
            float fa[8], fb[8];
            set8(*(const uint4*)(&As[row][cb]), fa);
            set8(*(const uint4*)(&As[row][cb + 8]), fb);
            uint2 pa = pack8_fp8(fa), pb = pack8_fp8(fb);
            uint4 v; v.x = pa.x; v.y = pa.y; v.z = pb.x; v.w = pb.y;
            *(uint4*)(hout8 + (size_t)(node0 + row) * 128 + cb) = v;
        }
    } else {
        // fused segment-sum pooling (batch sorted): run-length sum by graph.
        const int c = tid & 127;
        const int r0 = (tid >> 7) * 32;
        float accp = 0.f;
        int g0 = bsh[r0];
        for (int row = r0; row < r0 + 32; ++row) {
            int gg = bsh[row];
            if (gg != g0) {
                atomicAdd(&g_agg7[(size_t)g0 * 128 + c], accp);
                accp = 0.f; g0 = gg;
            }
            accp += __half2float(As[row][c]);
        }
        atomicAdd(&g_agg7[(size_t)g0 * 128 + c], accp);
    }
}

// ---------------- fused head: hidden in LDS, logits out (1 launch) --------

__global__ __launch_bounds__(256) void k_head(const float* __restrict__ Wc1,
                                              const float* __restrict__ bc1,
                                              const float* __restrict__ Wc2,
                                              const float* __restrict__ bc2,
                                              float* __restrict__ out) {
    __shared__ float hsh[4][64];
    const int g4 = blockIdx.x * 4;              // 4 graphs per block
    const int gi = g4 + (threadIdx.x >> 6);
    const int c = threadIdx.x & 63;
    const float* pooled = g_agg7;
    int cnt = g_gstart[gi + 1] - g_gstart[gi];
    float inv = 1.0f / (float)max(cnt, 1);
    float z = 0.f;
#pragma unroll 8
    for (int k = 0; k < 128; ++k) z = fmaf(pooled[(size_t)gi * 128 + k], Wc1[k * 64 + c], z);
    hsh[threadIdx.x >> 6][c] = fmaxf(fmaf(z, inv, bc1[c]), 0.f);
    __syncthreads();
    if (threadIdx.x < 4) {
        float zz = bc2[0];
#pragma unroll 8
        for (int k = 0; k < 64; ++k) zz = fmaf(hsh[threadIdx.x][k], Wc2[k], zz);
        out[g4 + threadIdx.x] = zz;
    }
}

// ---------------- launch ----------------

extern "C" void kernel_launch(void* const* d_in, const int* in_sizes, int n_in,
                              void* d_out, int out_size, void* d_ws, size_t ws_size,
                              hipStream_t stream) {
    const float* x     = (const float*)d_in[0];
    const int*   ei    = (const int*)d_in[1];
    const int*   batch = (const int*)d_in[2];
    const float* W1 = (const float*)d_in[3];
    const float* b1 = (const float*)d_in[4];
    const float* g1 = (const float*)d_in[5];
    const float* bt1= (const float*)d_in[6];
    const float* rm1= (const float*)d_in[7];
    const float* rv1= (const float*)d_in[8];
    const float* W2 = (const float*)d_in[9];
    const float* b2 = (const float*)d_in[10];
    const float* g2 = (const float*)d_in[11];
    const float* bt2= (const float*)d_in[12];
    const float* rm2= (const float*)d_in[13];
    const float* rv2= (const float*)d_in[14];
    const float* W3 = (const float*)d_in[15];
    const float* b3 = (const float*)d_in[16];
    const float* g3 = (const float*)d_in[17];
    const float* bt3= (const float*)d_in[18];
    const float* rm3= (const float*)d_in[19];
    const float* rv3= (const float*)d_in[20];
    const float* Wc1= (const float*)d_in[21];
    const float* bc1= (const float*)d_in[22];
    const float* Wc2= (const float*)d_in[23];
    const float* bc2= (const float*)d_in[24];
    float* outp = (float*)d_out;
    (void)d_ws; (void)ws_size; (void)n_in; (void)in_sizes;

    const int* srcp = ei;
    const int* dstp = ei + N_EDGES;

    // prep: zero rowcnt + wt1/wt2/wt3 transposes (covers 1,036,864 threads)
    k_prep<<<4051, 256, 0, stream>>>(W1, W2, W3);

    // CSR build (by dst); scan1 also emits dinv + px fp16x8
    k_hist<<<(N_EDGES + 255) / 256, 256, 0, stream>>>(dstp);
    k_scan1<<<NBLK1, 256, 0, stream>>>(x);
    k_scan2<<<1, 256, 0, stream>>>();
    k_scan3<<<NBLK1, 256, 0, stream>>>();
    k_scatter<<<(N_EDGES + 255) / 256, 256, 0, stream>>>(srcp, dstp);

    // graph boundaries + pooled-sum zeroing (1 launch)
    k_gz<<<4225, 256, 0, stream>>>(batch);

    // layer 1: fused gather+MFMA lin1+BN/ReLU -> q1 fp8
    k_l1_fused<<<N_NODES / 64, 256, 0, stream>>>(b1, g1, bt1, rm1, rv1);

    // layers 2,3: fused gather + MFMA GEMM
    k_agg_gemm<true,  true,  0, 1><<<N_NODES / 64, 256, 0, stream>>>(b2, g2, bt2, rm2, rv2, batch);
    k_agg_gemm<false, false, 1, 2><<<N_NODES / 64, 256, 0, stream>>>(b3, g3, bt3, rm3, rv3, batch);

    // fused head MLP
    k_head<<<N_GRAPHS / 4, 256, 0, stream>>>(Wc1, bc1, Wc2, bc2, outp);
}

// Round 9
// 1081.258 us; speedup vs baseline: 1.1044x; 1.0265x over previous
//
#include <hip/hip_runtime.h>
#include <hip/hip_fp16.h>

#define N_NODES 1000000
#define N_EDGES 4000000
#define N_GRAPHS 32768
#define BN_EPS 1e-5f
#define NBLK1 3907   // ceil(N_NODES/256)

typedef _Float16 f16;
typedef f16   f16x8 __attribute__((ext_vector_type(8)));
typedef float f32x4 __attribute__((ext_vector_type(4)));
typedef float f32x2 __attribute__((ext_vector_type(2)));

// ---------------------------------------------------------------------------
// Static device-global scratch.
// r21: gather-read features fp8 e4m3 (q1, h2). r22: h3 never materialized
// (fused pooling). r23: layer-1 fully fused. r24 degree-sort REGRESSED ->
// REVERTED. r25: launch consolidation. r26: 2-list interleaved gather
// (fp8-era register cost makes r18's MLP idea affordable).
// ---------------------------------------------------------------------------
__device__ __half g_hA[128000000];      // 256 MB: q1 fp8 (first 128 MB)
__device__ __half g_hB[128000000];      // 256 MB: px fp16x8 (16 MB) -> h2 fp8 (128 MB)
__device__ float  g_agg7[8400000];      //  33.6 MB: pooled SUMS
__device__ float  g_dinv[N_NODES];
__device__ int    g_rowcnt[N_NODES];
__device__ int    g_row_start[N_NODES + 1];
__device__ int    g_csr_src[N_EDGES];
__device__ int    g_part[NBLK1];
__device__ int    g_gstart[N_GRAPHS + 1];
__device__ __align__(16) __half g_wt1[4096];    // W1^T fp16 [n][k], K padded to 32
__device__ __align__(16) __half g_wt2[16384];   // W2^T fp16 [n][k]
__device__ __align__(16) __half g_wt3[16384];   // W3^T fp16 [n][k]

// ---------------- fp16 helpers ----------------

__device__ __forceinline__ void set8(uint4 raw, float f[8]) {
    __half2 h; float2 a;
    __builtin_memcpy(&h, &raw.x, 4); a = __half22float2(h); f[0] = a.x; f[1] = a.y;
    __builtin_memcpy(&h, &raw.y, 4); a = __half22float2(h); f[2] = a.x; f[3] = a.y;
    __builtin_memcpy(&h, &raw.z, 4); a = __half22float2(h); f[4] = a.x; f[5] = a.y;
    __builtin_memcpy(&h, &raw.w, 4); a = __half22float2(h); f[6] = a.x; f[7] = a.y;
}
__device__ __forceinline__ uint4 pack8(const float f[8]) {
    __half2 h0 = __floats2half2_rn(f[0], f[1]);
    __half2 h1 = __floats2half2_rn(f[2], f[3]);
    __half2 h2 = __floats2half2_rn(f[4], f[5]);
    __half2 h3 = __floats2half2_rn(f[6], f[7]);
    uint4 raw;
    __builtin_memcpy(&raw.x, &h0, 4);
    __builtin_memcpy(&raw.y, &h1, 4);
    __builtin_memcpy(&raw.z, &h2, 4);
    __builtin_memcpy(&raw.w, &h3, 4);
    return raw;
}
__device__ __forceinline__ f32x2 cvt2h(unsigned raw) {
    __half2 h; __builtin_memcpy(&h, &raw, 4);
    float2 a = __half22float2(h);
    f32x2 r; r.x = a.x; r.y = a.y; return r;
}

// ---------------- fp8 e4m3 helpers (vector f32x2 accumulators) ----------------

__device__ __forceinline__ void set8_fp8v(uint2 raw, f32x2 f[4]) {
    f[0] = __builtin_amdgcn_cvt_pk_f32_fp8(raw.x, false);
    f[1] = __builtin_amdgcn_cvt_pk_f32_fp8(raw.x, true);
    f[2] = __builtin_amdgcn_cvt_pk_f32_fp8(raw.y, false);
    f[3] = __builtin_amdgcn_cvt_pk_f32_fp8(raw.y, true);
}
__device__ __forceinline__ void add8_fp8v(uint2 raw, f32x2 f[4]) {
    f[0] += __builtin_amdgcn_cvt_pk_f32_fp8(raw.x, false);   // v_pk_add_f32
    f[1] += __builtin_amdgcn_cvt_pk_f32_fp8(raw.x, true);
    f[2] += __builtin_amdgcn_cvt_pk_f32_fp8(raw.y, false);
    f[3] += __builtin_amdgcn_cvt_pk_f32_fp8(raw.y, true);
}
__device__ __forceinline__ uint4 pack8v(const f32x2 f[4]) {
    __half2 h0 = __floats2half2_rn(f[0].x, f[0].y);
    __half2 h1 = __floats2half2_rn(f[1].x, f[1].y);
    __half2 h2 = __floats2half2_rn(f[2].x, f[2].y);
    __half2 h3 = __floats2half2_rn(f[3].x, f[3].y);
    uint4 raw;
    __builtin_memcpy(&raw.x, &h0, 4);
    __builtin_memcpy(&raw.y, &h1, 4);
    __builtin_memcpy(&raw.z, &h2, 4);
    __builtin_memcpy(&raw.w, &h3, 4);
    return raw;
}
__device__ __forceinline__ uint2 pack8_fp8(const float f[8]) {
    int lo = 0, hi = 0;
    lo = __builtin_amdgcn_cvt_pk_fp8_f32(f[0], f[1], lo, false);
    lo = __builtin_amdgcn_cvt_pk_fp8_f32(f[2], f[3], lo, true);
    hi = __builtin_amdgcn_cvt_pk_fp8_f32(f[4], f[5], hi, false);
    hi = __builtin_amdgcn_cvt_pk_fp8_f32(f[6], f[7], hi, true);
    uint2 r; r.x = (unsigned)lo; r.y = (unsigned)hi; return r;
}

// ---------------- prep: zero rowcnt + all weight transposes (1 launch) ----

__global__ __launch_bounds__(256) void k_prep(const float* __restrict__ W1,
                                              const float* __restrict__ W2,
                                              const float* __restrict__ W3) {
    int t = blockIdx.x * 256 + threadIdx.x;
    if (t < N_NODES) { g_rowcnt[t] = 0; return; }
    int u = t - N_NODES;
    if (u < 32768) {                       // W2/W3 -> fp16 transposed
        int sel = u >> 14, v = u & 16383;
        int n = v & 127, k = v >> 7;
        (sel ? g_wt3 : g_wt2)[n * 128 + k] = __float2half_rn((sel ? W3 : W2)[k * 128 + n]);
        return;
    }
    u -= 32768;
    if (u < 4096) {                        // W1^T fp16 [128][32], k>=7 zero
        int n = u & 127, k = u >> 7;
        g_wt1[n * 32 + k] = (k < 7) ? __float2half_rn(W1[k * 128 + n]) : __float2half_rn(0.f);
    }
}

// ---------------- CSR build ----------------

__global__ __launch_bounds__(256) void k_hist(const int* __restrict__ dst) {
    int e = blockIdx.x * 256 + threadIdx.x;
    if (e < N_EDGES) atomicAdd(&g_rowcnt[dst[e]], 1);
}

// scan1 also computes dinv AND px (fp16x8 row of dinv*x)
__global__ __launch_bounds__(256) void k_scan1(const float* __restrict__ x) {
    __shared__ int sh[256];
    int i = blockIdx.x * 256 + threadIdx.x;
    int v = (i < N_NODES) ? g_rowcnt[i] : 0;
    if (i < N_NODES) {
        float w = rsqrtf((float)(1 + v));   // +1 self-loop
        g_dinv[i] = w;
        float vv[8];
#pragma unroll
        for (int k = 0; k < 7; ++k) vv[k] = x[i * 7 + k] * w;
        vv[7] = 0.f;
        *(uint4*)(g_hB + (size_t)i * 8) = pack8(vv);
    }
    sh[threadIdx.x] = v;
    __syncthreads();
#pragma unroll
    for (int off = 1; off < 256; off <<= 1) {
        int t = (threadIdx.x >= off) ? sh[threadIdx.x - off] : 0;
        __syncthreads();
        sh[threadIdx.x] += t;
        __syncthreads();
    }
    int incl = sh[threadIdx.x];
    if (i < N_NODES) g_row_start[i] = incl - v;
    if (threadIdx.x == 255) g_part[blockIdx.x] = incl;
}

__global__ __launch_bounds__(256) void k_scan2() {
    __shared__ int sh[256];
    int base = threadIdx.x * 16;
    int local[16];
    int s = 0;
#pragma unroll
    for (int k = 0; k < 16; ++k) {
        local[k] = (base + k < NBLK1) ? g_part[base + k] : 0;
        s += local[k];
    }
    sh[threadIdx.x] = s;
    __syncthreads();
#pragma unroll
    for (int off = 1; off < 256; off <<= 1) {
        int t = (threadIdx.x >= off) ? sh[threadIdx.x - off] : 0;
        __syncthreads();
        sh[threadIdx.x] += t;
        __syncthreads();
    }
    int carry = sh[threadIdx.x] - s;
#pragma unroll
    for (int k = 0; k < 16; ++k) {
        if (base + k < NBLK1) {
            int t = local[k];
            g_part[base + k] = carry;
            carry += t;
        }
    }
}

__global__ __launch_bounds__(256) void k_scan3() {
    int i = blockIdx.x * 256 + threadIdx.x;
    if (i < N_NODES) {
        g_row_start[i] += g_part[blockIdx.x];
        g_rowcnt[i] = 0;
    }
    if (i == 0) g_row_start[N_NODES] = N_EDGES;
}

__global__ __launch_bounds__(256) void k_scatter(const int* __restrict__ src,
                                                 const int* __restrict__ dst) {
    int e = blockIdx.x * 256 + threadIdx.x;
    if (e >= N_EDGES) return;
    int d = dst[e];
    int pos = g_row_start[d] + atomicAdd(&g_rowcnt[d], 1);
    g_csr_src[pos] = src[e];
}

// ---------------- gstart + pooled zero (1 launch) ----------------

__global__ __launch_bounds__(256) void k_gz(const int* __restrict__ batch) {
    int blk = blockIdx.x;
    if (blk < 4096) {                      // zero pooled sums (16.78 MB)
        int t = blk * 256 + threadIdx.x;
        *(float4*)(g_agg7 + (size_t)t * 4) = make_float4(0.f, 0.f, 0.f, 0.f);
        return;
    }
    int gidx = (blk - 4096) * 256 + threadIdx.x;
    if (gidx > N_GRAPHS) return;
    int lo = 0, hi = N_NODES;
    while (lo < hi) {
        int mid = (lo + hi) >> 1;
        if (batch[mid] < gidx) lo = mid + 1; else hi = mid;
    }
    g_gstart[gidx] = lo;
}

// ---------------- fused layer-1: gather(px) + MFMA lin1 + BN/ReLU -> q1 fp8

__global__ __launch_bounds__(256, 7) void k_l1_fused(const float* __restrict__ b,
                                                     const float* __restrict__ g,
                                                     const float* __restrict__ bt,
                                                     const float* __restrict__ rm,
                                                     const float* __restrict__ rv) {
    const __half* __restrict__ px = g_hB;
    unsigned char* __restrict__ q1 = (unsigned char*)g_hA;

    __shared__ __half As[64][152];          // 19,456 B
    const int tid = threadIdx.x;
    const int node0 = blockIdx.x * 64;

    // ---- gather: 4 threads/node, one pass ----
    {
        const int slot = tid >> 2;          // 0..63
        const int q = tid & 3;              // channel pair
        int i = node0 + slot;
        f32x2 f = cvt2h(*(const unsigned*)(px + (size_t)i * 8 + q * 2));   // self
        int e = g_row_start[i], e1 = g_row_start[i + 1];
        for (; e + 4 <= e1; e += 4) {
            int s0 = g_csr_src[e + 0], s1 = g_csr_src[e + 1];
            int s2 = g_csr_src[e + 2], s3 = g_csr_src[e + 3];
            unsigned r0 = *(const unsigned*)(px + (size_t)s0 * 8 + q * 2);
            unsigned r1 = *(const unsigned*)(px + (size_t)s1 * 8 + q * 2);
            unsigned r2 = *(const unsigned*)(px + (size_t)s2 * 8 + q * 2);
            unsigned r3 = *(const unsigned*)(px + (size_t)s3 * 8 + q * 2);
            f += cvt2h(r0); f += cvt2h(r1); f += cvt2h(r2); f += cvt2h(r3);
        }
        for (; e < e1; ++e)
            f += cvt2h(*(const unsigned*)(px + (size_t)g_csr_src[e] * 8 + q * 2));
        __half2 hv = __floats2half2_rn(f.x, f.y);
        unsigned u; __builtin_memcpy(&u, &hv, 4);
        *(unsigned*)(&As[slot][q * 2]) = u;
        uint4 z; z.x = 0; z.y = 0; z.z = 0; z.w = 0;
        *(uint4*)(&As[slot][8 + q * 8]) = z;    // zero K pad halves 8..39
    }

    const int wv = tid >> 6;        // wave 0..3 -> cols [wv*32, wv*32+32)
    const int lane = tid & 63;
    const int lm = lane & 15;
    const int lq = lane >> 4;

    __syncthreads();

    // ---- MFMA: K=32 (single kb) ----
    f32x4 acc[4][2];
#pragma unroll
    for (int mt = 0; mt < 4; ++mt)
#pragma unroll
        for (int nt = 0; nt < 2; ++nt) acc[mt][nt] = (f32x4){0.f, 0.f, 0.f, 0.f};

    f16x8 bq[2];
#pragma unroll
    for (int nt = 0; nt < 2; ++nt)
        __builtin_memcpy(&bq[nt], g_wt1 + (size_t)(wv * 32 + nt * 16 + lm) * 32 + lq * 8, 16);
#pragma unroll
    for (int mt = 0; mt < 4; ++mt) {
        f16x8 afr;
        __builtin_memcpy(&afr, &As[mt * 16 + lm][lq * 8], 16);
#pragma unroll
        for (int nt = 0; nt < 2; ++nt)
            acc[mt][nt] = __builtin_amdgcn_mfma_f32_16x16x32_f16(afr, bq[nt], acc[mt][nt], 0, 0, 0);
    }

    float4 dv4[4];
#pragma unroll
    for (int mt = 0; mt < 4; ++mt)
        dv4[mt] = *(const float4*)(g_dinv + node0 + mt * 16 + lq * 4);

    __syncthreads();   // all As gather reads done before C staging

    // ---- epilogue: BN/ReLU (PRE), stage C fp16 in As ----
#pragma unroll
    for (int nt = 0; nt < 2; ++nt) {
        int c = wv * 32 + nt * 16 + lm;
        float s = g[c] * rsqrtf(rv[c] + BN_EPS);
        float o = fmaf(b[c] - rm[c], s, bt[c]);
#pragma unroll
        for (int mt = 0; mt < 4; ++mt) {
            float dvr[4] = {dv4[mt].x, dv4[mt].y, dv4[mt].z, dv4[mt].w};
#pragma unroll
            for (int r = 0; r < 4; ++r) {
                float y = fmaxf(fmaf(acc[mt][nt][r] * dvr[r], s, o), 0.f) * dvr[r];
                As[mt * 16 + lq * 4 + r][c] = __float2half_rn(y);
            }
        }
    }
    __syncthreads();
#pragma unroll
    for (int i = 0; i < 2; ++i) {
        int u = tid + i * 256;                 // 0..511
        int row = u >> 3, cb = (u & 7) * 16;   // 16 cols/thread
        float fa[8], fb[8];
        set8(*(const uint4*)(&As[row][cb]), fa);
        set8(*(const uint4*)(&As[row][cb + 8]), fb);
        uint2 pa = pack8_fp8(fa), pb = pack8_fp8(fb);
        uint4 v; v.x = pa.x; v.y = pa.y; v.z = pb.x; v.w = pb.y;
        *(uint4*)(q1 + (size_t)(node0 + row) * 128 + cb) = v;
    }
}

// ---------------- fused CSR-gather + MFMA GEMM + BN + ReLU (layers 2,3) ----
// LEDGER:
//  r18 interleaved gather (fp16 era) -> reg spills (uint4 rows = 32 regs).
//  r19 nt stores -> WRITE x5. REVERTED. r19b bounds(256,8) -> spill thrash.
//  r20 occupancy 55->79%, dur flat (was HBM-bound). r21 fp8 rows: 374->277.
//  r22 fused pooling: 277->237. r23 l1 fused. r24 degree-sort REGRESSED
//      (FETCH 320->603) -> REVERTED.
//  r26 THIS: top-down concurrency arithmetic says ~1.4 lines in flight/wave
//      (10M lines, ~6k waves, 237us, ~500cy) -> per-wave-MLP-bound. 2-list
//      interleave now costs only ~58 VGPR (fp8 uint2 rows): 8 row loads in
//      flight/lane. Clamped+zeroed batches (fp8 0x00 == 0.0, sums exact).
//      Canaries: WRITE flat (no spill), FETCH flat (clamp innocent),
//      absmax bit-identical.
// OUTMODE: 1 = fp8 row store (layer 2), 2 = fused pool (layer 3).

template <bool PRE, bool ATOB, int WSEL, int OUTMODE>
__global__ __launch_bounds__(256, 7) void k_agg_gemm(const float* __restrict__ b,
                                                     const float* __restrict__ g,
                                                     const float* __restrict__ bt,
                                                     const float* __restrict__ rm,
                                                     const float* __restrict__ rv,
                                                     const int* __restrict__ batch) {
    const unsigned char* __restrict__ hin8 =
        (const unsigned char*)(ATOB ? g_hA : g_hB);          // fp8 rows, 128 B
    unsigned char* __restrict__ hout8 =
        (unsigned char*)(ATOB ? g_hB : g_hA);                // fp8 rows, 128 B
    const __half* __restrict__ WtG = (WSEL == 0) ? g_wt2 : g_wt3;

    __shared__ __half As[64][152];          // 19,456 B
    __shared__ int bsh[64];
    const int tid = threadIdx.x;
    const int node0 = blockIdx.x * 64;

    // ---- gather: 2-list interleave, clamped+zeroed 4-edge batches ----
    {
        const int slot = tid >> 4;          // 0..15
        const int c0 = (tid & 15) * 8;      // 8 channels = 8 fp8 bytes
#pragma unroll
        for (int pair = 0; pair < 2; ++pair) {
            const int iA = node0 + (pair * 2 + 0) * 16 + slot;
            const int iB = node0 + (pair * 2 + 1) * 16 + slot;
            f32x2 fA[4], fB[4];
            set8_fp8v(*(const uint2*)(hin8 + (size_t)iA * 128 + c0), fA);   // self A
            set8_fp8v(*(const uint2*)(hin8 + (size_t)iB * 128 + c0), fB);   // self B
            const int eA = g_row_start[iA], e1A = g_row_start[iA + 1];
            const int eB = g_row_start[iB], e1B = g_row_start[iB + 1];
            const int dmax = max(e1A - eA, e1B - eB);
            for (int done = 0; done < dmax; done += 4) {
                const int bA = eA + done, bB = eB + done;
                const int emA = min(max(e1A - 1, bA), N_EDGES - 1);
                const int emB = min(max(e1B - 1, bB), N_EDGES - 1);
                int sA0 = g_csr_src[min(bA,     emA)];
                int sA1 = g_csr_src[min(bA + 1, emA)];
                int sA2 = g_csr_src[min(bA + 2, emA)];
                int sA3 = g_csr_src[min(bA + 3, emA)];
                int sB0 = g_csr_src[min(bB,     emB)];
                int sB1 = g_csr_src[min(bB + 1, emB)];
                int sB2 = g_csr_src[min(bB + 2, emB)];
                int sB3 = g_csr_src[min(bB + 3, emB)];
                uint2 rA0 = *(const uint2*)(hin8 + (size_t)sA0 * 128 + c0);
                uint2 rA1 = *(const uint2*)(hin8 + (size_t)sA1 * 128 + c0);
                uint2 rA2 = *(const uint2*)(hin8 + (size_t)sA2 * 128 + c0);
                uint2 rA3 = *(const uint2*)(hin8 + (size_t)sA3 * 128 + c0);
                uint2 rB0 = *(const uint2*)(hin8 + (size_t)sB0 * 128 + c0);
                uint2 rB1 = *(const uint2*)(hin8 + (size_t)sB1 * 128 + c0);
                uint2 rB2 = *(const uint2*)(hin8 + (size_t)sB2 * 128 + c0);
                uint2 rB3 = *(const uint2*)(hin8 + (size_t)sB3 * 128 + c0);
                __builtin_amdgcn_sched_barrier(0);   // keep the 8 row loads clustered
                if (bA     >= e1A) { rA0.x = 0u; rA0.y = 0u; }   // fp8 0x00 == 0.0
                if (bA + 1 >= e1A) { rA1.x = 0u; rA1.y = 0u; }
                if (bA + 2 >= e1A) { rA2.x = 0u; rA2.y = 0u; }
                if (bA + 3 >= e1A) { rA3.x = 0u; rA3.y = 0u; }
                if (bB     >= e1B) { rB0.x = 0u; rB0.y = 0u; }
                if (bB + 1 >= e1B) { rB1.x = 0u; rB1.y = 0u; }
                if (bB + 2 >= e1B) { rB2.x = 0u; rB2.y = 0u; }
                if (bB + 3 >= e1B) { rB3.x = 0u; rB3.y = 0u; }
                add8_fp8v(rA0, fA); add8_fp8v(rA1, fA); add8_fp8v(rA2, fA); add8_fp8v(rA3, fA);
                add8_fp8v(rB0, fB); add8_fp8v(rB1, fB); add8_fp8v(rB2, fB); add8_fp8v(rB3, fB);
            }
            *(uint4*)(&As[(pair * 2 + 0) * 16 + slot][c0]) = pack8v(fA);
            *(uint4*)(&As[(pair * 2 + 1) * 16 + slot][c0]) = pack8v(fB);
        }
    }

    const int wv = tid >> 6;        // wave 0..3 -> cols [wv*32, wv*32+32)
    const int lane = tid & 63;
    const int lm = lane & 15;
    const int lq = lane >> 4;

    __syncthreads();

    // ---- MFMA: kb-outer so only 2 B-frags live at a time ----
    f32x4 acc[4][2];
#pragma unroll
    for (int mt = 0; mt < 4; ++mt)
#pragma unroll
        for (int nt = 0; nt < 2; ++nt) acc[mt][nt] = (f32x4){0.f, 0.f, 0.f, 0.f};

#pragma unroll
    for (int kb = 0; kb < 4; ++kb) {
        f16x8 bq[2];
#pragma unroll
        for (int nt = 0; nt < 2; ++nt)
            __builtin_memcpy(&bq[nt],
                             WtG + (size_t)(wv * 32 + nt * 16 + lm) * 128 + kb * 32 + lq * 8, 16);
#pragma unroll
        for (int mt = 0; mt < 4; ++mt) {
            f16x8 afr;
            __builtin_memcpy(&afr, &As[mt * 16 + lm][kb * 32 + lq * 8], 16);
#pragma unroll
            for (int nt = 0; nt < 2; ++nt)
                acc[mt][nt] = __builtin_amdgcn_mfma_f32_16x16x32_f16(afr, bq[nt], acc[mt][nt], 0, 0, 0);
        }
    }

    float4 dv4[4];
#pragma unroll
    for (int mt = 0; mt < 4; ++mt)
        dv4[mt] = *(const float4*)(g_dinv + node0 + mt * 16 + lq * 4);

    if (OUTMODE == 2 && tid < 64) bsh[tid] = batch[node0 + tid];

    __syncthreads();

    // ---- epilogue: BN/ReLU, stage C (fp16) in As ----
#pragma unroll
    for (int nt = 0; nt < 2; ++nt) {
        int c = wv * 32 + nt * 16 + lm;
        float s = g[c] * rsqrtf(rv[c] + BN_EPS);
        float o = fmaf(b[c] - rm[c], s, bt[c]);
#pragma unroll
        for (int mt = 0; mt < 4; ++mt) {
            float dvr[4] = {dv4[mt].x, dv4[mt].y, dv4[mt].z, dv4[mt].w};
#pragma unroll
            for (int r = 0; r < 4; ++r) {
                float pm = PRE ? dvr[r] : 1.0f;
                float y = fmaxf(fmaf(acc[mt][nt][r] * dvr[r], s, o), 0.f) * pm;
                As[mt * 16 + lq * 4 + r][c] = __float2half_rn(y);
            }
        }
    }
    __syncthreads();

    if (OUTMODE == 1) {
#pragma unroll
        for (int i = 0; i < 2; ++i) {
            int u = tid + i * 256;                 // 0..511
            int row = u >> 3, cb = (u & 7) * 16;   // 16 cols/thread
            float fa[8], fb[8];
            set8(*(const uint4*)(&As[row][cb]), fa);
            set8(*(const uint4*)(&As[row][cb + 8]), fb);
            uint2 pa = pack8_fp8(fa), pb = pack8_fp8(fb);
            uint4 v; v.x = pa.x; v.y = pa.y; v.z = pb.x; v.w = pb.y;
            *(uint4*)(hout8 + (size_t)(node0 + row) * 128 + cb) = v;
        }
    } else {
        // fused segment-sum pooling (batch sorted): run-length sum by graph.
        const int c = tid & 127;
        const int r0 = (tid >> 7) * 32;
        float accp = 0.f;
        int g0 = bsh[r0];
        for (int row = r0; row < r0 + 32; ++row) {
            int gg = bsh[row];
            if (gg != g0) {
                atomicAdd(&g_agg7[(size_t)g0 * 128 + c], accp);
                accp = 0.f; g0 = gg;
            }
            accp += __half2float(As[row][c]);
        }
        atomicAdd(&g_agg7[(size_t)g0 * 128 + c], accp);
    }
}

// ---------------- fused head: hidden in LDS, logits out (1 launch) --------

__global__ __launch_bounds__(256) void k_head(const float* __restrict__ Wc1,
                                              const float* __restrict__ bc1,
                                              const float* __restrict__ Wc2,
                                              const float* __restrict__ bc2,
                                              float* __restrict__ out) {
    __shared__ float hsh[4][64];
    const int g4 = blockIdx.x * 4;              // 4 graphs per block
    const int gi = g4 + (threadIdx.x >> 6);
    const int c = threadIdx.x & 63;
    const float* pooled = g_agg7;
    int cnt = g_gstart[gi + 1] - g_gstart[gi];
    float inv = 1.0f / (float)max(cnt, 1);
    float z = 0.f;
#pragma unroll 8
    for (int k = 0; k < 128; ++k) z = fmaf(pooled[(size_t)gi * 128 + k], Wc1[k * 64 + c], z);
    hsh[threadIdx.x >> 6][c] = fmaxf(fmaf(z, inv, bc1[c]), 0.f);
    __syncthreads();
    if (threadIdx.x < 4) {
        float zz = bc2[0];
#pragma unroll 8
        for (int k = 0; k < 64; ++k) zz = fmaf(hsh[threadIdx.x][k], Wc2[k], zz);
        out[g4 + threadIdx.x] = zz;
    }
}

// ---------------- launch ----------------

extern "C" void kernel_launch(void* const* d_in, const int* in_sizes, int n_in,
                              void* d_out, int out_size, void* d_ws, size_t ws_size,
                              hipStream_t stream) {
    const float* x     = (const float*)d_in[0];
    const int*   ei    = (const int*)d_in[1];
    const int*   batch = (const int*)d_in[2];
    const float* W1 = (const float*)d_in[3];
    const float* b1 = (const float*)d_in[4];
    const float* g1 = (const float*)d_in[5];
    const float* bt1= (const float*)d_in[6];
    const float* rm1= (const float*)d_in[7];
    const float* rv1= (const float*)d_in[8];
    const float* W2 = (const float*)d_in[9];
    const float* b2 = (const float*)d_in[10];
    const float* g2 = (const float*)d_in[11];
    const float* bt2= (const float*)d_in[12];
    const float* rm2= (const float*)d_in[13];
    const float* rv2= (const float*)d_in[14];
    const float* W3 = (const float*)d_in[15];
    const float* b3 = (const float*)d_in[16];
    const float* g3 = (const float*)d_in[17];
    const float* bt3= (const float*)d_in[18];
    const float* rm3= (const float*)d_in[19];
    const float* rv3= (const float*)d_in[20];
    const float* Wc1= (const float*)d_in[21];
    const float* bc1= (const float*)d_in[22];
    const float* Wc2= (const float*)d_in[23];
    const float* bc2= (const float*)d_in[24];
    float* outp = (float*)d_out;
    (void)d_ws; (void)ws_size; (void)n_in; (void)in_sizes;

    const int* srcp = ei;
    const int* dstp = ei + N_EDGES;

    // prep: zero rowcnt + wt1/wt2/wt3 transposes
    k_prep<<<4051, 256, 0, stream>>>(W1, W2, W3);

    // CSR build (by dst); scan1 also emits dinv + px fp16x8
    k_hist<<<(N_EDGES + 255) / 256, 256, 0, stream>>>(dstp);
    k_scan1<<<NBLK1, 256, 0, stream>>>(x);
    k_scan2<<<1, 256, 0, stream>>>();
    k_scan3<<<NBLK1, 256, 0, stream>>>();
    k_scatter<<<(N_EDGES + 255) / 256, 256, 0, stream>>>(srcp, dstp);

    // graph boundaries + pooled-sum zeroing (1 launch)
    k_gz<<<4225, 256, 0, stream>>>(batch);

    // layer 1: fused gather+MFMA lin1+BN/ReLU -> q1 fp8
    k_l1_fused<<<N_NODES / 64, 256, 0, stream>>>(b1, g1, bt1, rm1, rv1);

    // layers 2,3: fused gather + MFMA GEMM
    k_agg_gemm<true,  true,  0, 1><<<N_NODES / 64, 256, 0, stream>>>(b2, g2, bt2, rm2, rv2, batch);
    k_agg_gemm<false, false, 1, 2><<<N_NODES / 64, 256, 0, stream>>>(b3, g3, bt3, rm3, rv3, batch);

    // fused head MLP
    k_head<<<N_GRAPHS / 4, 256, 0, stream>>>(Wc1, bc1, Wc2, bc2, outp);
}

// Round 10
// 1061.725 us; speedup vs baseline: 1.1247x; 1.0184x over previous
//
#include <hip/hip_runtime.h>
#include <hip/hip_fp16.h>

#define N_NODES 1000000
#define N_EDGES 4000000
#define N_GRAPHS 32768
#define BN_EPS 1e-5f
#define NBLK1 3907   // ceil(N_NODES/256)

typedef _Float16 f16;
typedef f16   f16x8 __attribute__((ext_vector_type(8)));
typedef float f32x4 __attribute__((ext_vector_type(4)));
typedef float f32x2 __attribute__((ext_vector_type(2)));

// ---------------------------------------------------------------------------
// Static device-global scratch.
// r21: fp8 e4m3 gather rows. r22: fused pooling (no h3). r23: l1 fused.
// r24 degree-sort REGRESSED -> REVERTED. r25: launch consolidation.
// r26: 2-list interleaved gather (+MLP, dur 237->219) BUT clamp bug read
// past list end (FETCH 320->568 MB). r27: clamp to own last edge.
// ---------------------------------------------------------------------------
__device__ __half g_hA[128000000];      // 256 MB: q1 fp8 (first 128 MB)
__device__ __half g_hB[128000000];      // 256 MB: px fp16x8 (16 MB) -> h2 fp8 (128 MB)
__device__ float  g_agg7[8400000];      //  33.6 MB: pooled SUMS
__device__ float  g_dinv[N_NODES];
__device__ int    g_rowcnt[N_NODES];
__device__ int    g_row_start[N_NODES + 1];
__device__ int    g_csr_src[N_EDGES];
__device__ int    g_part[NBLK1];
__device__ int    g_gstart[N_GRAPHS + 1];
__device__ __align__(16) __half g_wt1[4096];    // W1^T fp16 [n][k], K padded to 32
__device__ __align__(16) __half g_wt2[16384];   // W2^T fp16 [n][k]
__device__ __align__(16) __half g_wt3[16384];   // W3^T fp16 [n][k]

// ---------------- fp16 helpers ----------------

__device__ __forceinline__ void set8(uint4 raw, float f[8]) {
    __half2 h; float2 a;
    __builtin_memcpy(&h, &raw.x, 4); a = __half22float2(h); f[0] = a.x; f[1] = a.y;
    __builtin_memcpy(&h, &raw.y, 4); a = __half22float2(h); f[2] = a.x; f[3] = a.y;
    __builtin_memcpy(&h, &raw.z, 4); a = __half22float2(h); f[4] = a.x; f[5] = a.y;
    __builtin_memcpy(&h, &raw.w, 4); a = __half22float2(h); f[6] = a.x; f[7] = a.y;
}
__device__ __forceinline__ uint4 pack8(const float f[8]) {
    __half2 h0 = __floats2half2_rn(f[0], f[1]);
    __half2 h1 = __floats2half2_rn(f[2], f[3]);
    __half2 h2 = __floats2half2_rn(f[4], f[5]);
    __half2 h3 = __floats2half2_rn(f[6], f[7]);
    uint4 raw;
    __builtin_memcpy(&raw.x, &h0, 4);
    __builtin_memcpy(&raw.y, &h1, 4);
    __builtin_memcpy(&raw.z, &h2, 4);
    __builtin_memcpy(&raw.w, &h3, 4);
    return raw;
}
__device__ __forceinline__ f32x2 cvt2h(unsigned raw) {
    __half2 h; __builtin_memcpy(&h, &raw, 4);
    float2 a = __half22float2(h);
    f32x2 r; r.x = a.x; r.y = a.y; return r;
}

// ---------------- fp8 e4m3 helpers (vector f32x2 accumulators) ----------------

__device__ __forceinline__ void set8_fp8v(uint2 raw, f32x2 f[4]) {
    f[0] = __builtin_amdgcn_cvt_pk_f32_fp8(raw.x, false);
    f[1] = __builtin_amdgcn_cvt_pk_f32_fp8(raw.x, true);
    f[2] = __builtin_amdgcn_cvt_pk_f32_fp8(raw.y, false);
    f[3] = __builtin_amdgcn_cvt_pk_f32_fp8(raw.y, true);
}
__device__ __forceinline__ void add8_fp8v(uint2 raw, f32x2 f[4]) {
    f[0] += __builtin_amdgcn_cvt_pk_f32_fp8(raw.x, false);   // v_pk_add_f32
    f[1] += __builtin_amdgcn_cvt_pk_f32_fp8(raw.x, true);
    f[2] += __builtin_amdgcn_cvt_pk_f32_fp8(raw.y, false);
    f[3] += __builtin_amdgcn_cvt_pk_f32_fp8(raw.y, true);
}
__device__ __forceinline__ uint4 pack8v(const f32x2 f[4]) {
    __half2 h0 = __floats2half2_rn(f[0].x, f[0].y);
    __half2 h1 = __floats2half2_rn(f[1].x, f[1].y);
    __half2 h2 = __floats2half2_rn(f[2].x, f[2].y);
    __half2 h3 = __floats2half2_rn(f[3].x, f[3].y);
    uint4 raw;
    __builtin_memcpy(&raw.x, &h0, 4);
    __builtin_memcpy(&raw.y, &h1, 4);
    __builtin_memcpy(&raw.z, &h2, 4);
    __builtin_memcpy(&raw.w, &h3, 4);
    return raw;
}
__device__ __forceinline__ uint2 pack8_fp8(const float f[8]) {
    int lo = 0, hi = 0;
    lo = __builtin_amdgcn_cvt_pk_fp8_f32(f[0], f[1], lo, false);
    lo = __builtin_amdgcn_cvt_pk_fp8_f32(f[2], f[3], lo, true);
    hi = __builtin_amdgcn_cvt_pk_fp8_f32(f[4], f[5], hi, false);
    hi = __builtin_amdgcn_cvt_pk_fp8_f32(f[6], f[7], hi, true);
    uint2 r; r.x = (unsigned)lo; r.y = (unsigned)hi; return r;
}

// ---------------- prep: zero rowcnt + all weight transposes (1 launch) ----

__global__ __launch_bounds__(256) void k_prep(const float* __restrict__ W1,
                                              const float* __restrict__ W2,
                                              const float* __restrict__ W3) {
    int t = blockIdx.x * 256 + threadIdx.x;
    if (t < N_NODES) { g_rowcnt[t] = 0; return; }
    int u = t - N_NODES;
    if (u < 32768) {                       // W2/W3 -> fp16 transposed
        int sel = u >> 14, v = u & 16383;
        int n = v & 127, k = v >> 7;
        (sel ? g_wt3 : g_wt2)[n * 128 + k] = __float2half_rn((sel ? W3 : W2)[k * 128 + n]);
        return;
    }
    u -= 32768;
    if (u < 4096) {                        // W1^T fp16 [128][32], k>=7 zero
        int n = u & 127, k = u >> 7;
        g_wt1[n * 32 + k] = (k < 7) ? __float2half_rn(W1[k * 128 + n]) : __float2half_rn(0.f);
    }
}

// ---------------- CSR build ----------------

__global__ __launch_bounds__(256) void k_hist(const int* __restrict__ dst) {
    int e = blockIdx.x * 256 + threadIdx.x;
    if (e < N_EDGES) atomicAdd(&g_rowcnt[dst[e]], 1);
}

// scan1 also computes dinv AND px (fp16x8 row of dinv*x)
__global__ __launch_bounds__(256) void k_scan1(const float* __restrict__ x) {
    __shared__ int sh[256];
    int i = blockIdx.x * 256 + threadIdx.x;
    int v = (i < N_NODES) ? g_rowcnt[i] : 0;
    if (i < N_NODES) {
        float w = rsqrtf((float)(1 + v));   // +1 self-loop
        g_dinv[i] = w;
        float vv[8];
#pragma unroll
        for (int k = 0; k < 7; ++k) vv[k] = x[i * 7 + k] * w;
        vv[7] = 0.f;
        *(uint4*)(g_hB + (size_t)i * 8) = pack8(vv);
    }
    sh[threadIdx.x] = v;
    __syncthreads();
#pragma unroll
    for (int off = 1; off < 256; off <<= 1) {
        int t = (threadIdx.x >= off) ? sh[threadIdx.x - off] : 0;
        __syncthreads();
        sh[threadIdx.x] += t;
        __syncthreads();
    }
    int incl = sh[threadIdx.x];
    if (i < N_NODES) g_row_start[i] = incl - v;
    if (threadIdx.x == 255) g_part[blockIdx.x] = incl;
}

__global__ __launch_bounds__(256) void k_scan2() {
    __shared__ int sh[256];
    int base = threadIdx.x * 16;
    int local[16];
    int s = 0;
#pragma unroll
    for (int k = 0; k < 16; ++k) {
        local[k] = (base + k < NBLK1) ? g_part[base + k] : 0;
        s += local[k];
    }
    sh[threadIdx.x] = s;
    __syncthreads();
#pragma unroll
    for (int off = 1; off < 256; off <<= 1) {
        int t = (threadIdx.x >= off) ? sh[threadIdx.x - off] : 0;
        __syncthreads();
        sh[threadIdx.x] += t;
        __syncthreads();
    }
    int carry = sh[threadIdx.x] - s;
#pragma unroll
    for (int k = 0; k < 16; ++k) {
        if (base + k < NBLK1) {
            int t = local[k];
            g_part[base + k] = carry;
            carry += t;
        }
    }
}

__global__ __launch_bounds__(256) void k_scan3() {
    int i = blockIdx.x * 256 + threadIdx.x;
    if (i < N_NODES) {
        g_row_start[i] += g_part[blockIdx.x];
        g_rowcnt[i] = 0;
    }
    if (i == 0) g_row_start[N_NODES] = N_EDGES;
}

__global__ __launch_bounds__(256) void k_scatter(const int* __restrict__ src,
                                                 const int* __restrict__ dst) {
    int e = blockIdx.x * 256 + threadIdx.x;
    if (e >= N_EDGES) return;
    int d = dst[e];
    int pos = g_row_start[d] + atomicAdd(&g_rowcnt[d], 1);
    g_csr_src[pos] = src[e];
}

// ---------------- gstart + pooled zero (1 launch) ----------------

__global__ __launch_bounds__(256) void k_gz(const int* __restrict__ batch) {
    int blk = blockIdx.x;
    if (blk < 4096) {                      // zero pooled sums (16.78 MB)
        int t = blk * 256 + threadIdx.x;
        *(float4*)(g_agg7 + (size_t)t * 4) = make_float4(0.f, 0.f, 0.f, 0.f);
        return;
    }
    int gidx = (blk - 4096) * 256 + threadIdx.x;
    if (gidx > N_GRAPHS) return;
    int lo = 0, hi = N_NODES;
    while (lo < hi) {
        int mid = (lo + hi) >> 1;
        if (batch[mid] < gidx) lo = mid + 1; else hi = mid;
    }
    g_gstart[gidx] = lo;
}

// ---------------- fused layer-1: gather(px) + MFMA lin1 + BN/ReLU -> q1 fp8

__global__ __launch_bounds__(256, 7) void k_l1_fused(const float* __restrict__ b,
                                                     const float* __restrict__ g,
                                                     const float* __restrict__ bt,
                                                     const float* __restrict__ rm,
                                                     const float* __restrict__ rv) {
    const __half* __restrict__ px = g_hB;
    unsigned char* __restrict__ q1 = (unsigned char*)g_hA;

    __shared__ __half As[64][152];          // 19,456 B
    const int tid = threadIdx.x;
    const int node0 = blockIdx.x * 64;

    // ---- gather: 4 threads/node, one pass ----
    {
        const int slot = tid >> 2;          // 0..63
        const int q = tid & 3;              // channel pair
        int i = node0 + slot;
        f32x2 f = cvt2h(*(const unsigned*)(px + (size_t)i * 8 + q * 2));   // self
        int e = g_row_start[i], e1 = g_row_start[i + 1];
        for (; e + 4 <= e1; e += 4) {
            int s0 = g_csr_src[e + 0], s1 = g_csr_src[e + 1];
            int s2 = g_csr_src[e + 2], s3 = g_csr_src[e + 3];
            unsigned r0 = *(const unsigned*)(px + (size_t)s0 * 8 + q * 2);
            unsigned r1 = *(const unsigned*)(px + (size_t)s1 * 8 + q * 2);
            unsigned r2 = *(const unsigned*)(px + (size_t)s2 * 8 + q * 2);
            unsigned r3 = *(const unsigned*)(px + (size_t)s3 * 8 + q * 2);
            f += cvt2h(r0); f += cvt2h(r1); f += cvt2h(r2); f += cvt2h(r3);
        }
        for (; e < e1; ++e)
            f += cvt2h(*(const unsigned*)(px + (size_t)g_csr_src[e] * 8 + q * 2));
        __half2 hv = __floats2half2_rn(f.x, f.y);
        unsigned u; __builtin_memcpy(&u, &hv, 4);
        *(unsigned*)(&As[slot][q * 2]) = u;
        uint4 z; z.x = 0; z.y = 0; z.z = 0; z.w = 0;
        *(uint4*)(&As[slot][8 + q * 8]) = z;    // zero K pad halves 8..39
    }

    const int wv = tid >> 6;        // wave 0..3 -> cols [wv*32, wv*32+32)
    const int lane = tid & 63;
    const int lm = lane & 15;
    const int lq = lane >> 4;

    __syncthreads();

    // ---- MFMA: K=32 (single kb) ----
    f32x4 acc[4][2];
#pragma unroll
    for (int mt = 0; mt < 4; ++mt)
#pragma unroll
        for (int nt = 0; nt < 2; ++nt) acc[mt][nt] = (f32x4){0.f, 0.f, 0.f, 0.f};

    f16x8 bq[2];
#pragma unroll
    for (int nt = 0; nt < 2; ++nt)
        __builtin_memcpy(&bq[nt], g_wt1 + (size_t)(wv * 32 + nt * 16 + lm) * 32 + lq * 8, 16);
#pragma unroll
    for (int mt = 0; mt < 4; ++mt) {
        f16x8 afr;
        __builtin_memcpy(&afr, &As[mt * 16 + lm][lq * 8], 16);
#pragma unroll
        for (int nt = 0; nt < 2; ++nt)
            acc[mt][nt] = __builtin_amdgcn_mfma_f32_16x16x32_f16(afr, bq[nt], acc[mt][nt], 0, 0, 0);
    }

    float4 dv4[4];
#pragma unroll
    for (int mt = 0; mt < 4; ++mt)
        dv4[mt] = *(const float4*)(g_dinv + node0 + mt * 16 + lq * 4);

    __syncthreads();   // all As gather reads done before C staging

    // ---- epilogue: BN/ReLU (PRE), stage C fp16 in As ----
#pragma unroll
    for (int nt = 0; nt < 2; ++nt) {
        int c = wv * 32 + nt * 16 + lm;
        float s = g[c] * rsqrtf(rv[c] + BN_EPS);
        float o = fmaf(b[c] - rm[c], s, bt[c]);
#pragma unroll
        for (int mt = 0; mt < 4; ++mt) {
            float dvr[4] = {dv4[mt].x, dv4[mt].y, dv4[mt].z, dv4[mt].w};
#pragma unroll
            for (int r = 0; r < 4; ++r) {
                float y = fmaxf(fmaf(acc[mt][nt][r] * dvr[r], s, o), 0.f) * dvr[r];
                As[mt * 16 + lq * 4 + r][c] = __float2half_rn(y);
            }
        }
    }
    __syncthreads();
#pragma unroll
    for (int i = 0; i < 2; ++i) {
        int u = tid + i * 256;                 // 0..511
        int row = u >> 3, cb = (u & 7) * 16;   // 16 cols/thread
        float fa[8], fb[8];
        set8(*(const uint4*)(&As[row][cb]), fa);
        set8(*(const uint4*)(&As[row][cb + 8]), fb);
        uint2 pa = pack8_fp8(fa), pb = pack8_fp8(fb);
        uint4 v; v.x = pa.x; v.y = pa.y; v.z = pb.x; v.w = pb.y;
        *(uint4*)(q1 + (size_t)(node0 + row) * 128 + cb) = v;
    }
}

// ---------------- fused CSR-gather + MFMA GEMM + BN + ReLU (layers 2,3) ----
// LEDGER:
//  r18 interleaved gather (fp16 era) -> reg spills. r19 nt stores -> WRITE
//  x5. r19b bounds(256,8) -> spill thrash. r20 occ up, dur flat.
//  r21 fp8 rows 374->277. r22 fused pooling 277->237. r23 l1 fused.
//  r24 degree-sort REGRESSED. r26 2-list interleave: dur 237->219 (MLP
//      works: VALU 35->49) BUT clamp `max(e1-1,b)` read PAST list end ->
//      random garbage rows, FETCH 320->568 MB (zeroed, so absmax exact).
//  r27 THIS: clamp to own last edge em=min(max(e1-1,e),NE-1) — exhausted
//      rounds re-read the node's own last neighbor row (L2-hit, ~free).
// OUTMODE: 1 = fp8 row store (layer 2), 2 = fused pool (layer 3).

template <bool PRE, bool ATOB, int WSEL, int OUTMODE>
__global__ __launch_bounds__(256, 7) void k_agg_gemm(const float* __restrict__ b,
                                                     const float* __restrict__ g,
                                                     const float* __restrict__ bt,
                                                     const float* __restrict__ rm,
                                                     const float* __restrict__ rv,
                                                     const int* __restrict__ batch) {
    const unsigned char* __restrict__ hin8 =
        (const unsigned char*)(ATOB ? g_hA : g_hB);          // fp8 rows, 128 B
    unsigned char* __restrict__ hout8 =
        (unsigned char*)(ATOB ? g_hB : g_hA);                // fp8 rows, 128 B
    const __half* __restrict__ WtG = (WSEL == 0) ? g_wt2 : g_wt3;

    __shared__ __half As[64][152];          // 19,456 B
    __shared__ int bsh[64];
    const int tid = threadIdx.x;
    const int node0 = blockIdx.x * 64;

    // ---- gather: 2-list interleave, clamped-to-own-last-edge batches ----
    {
        const int slot = tid >> 4;          // 0..15
        const int c0 = (tid & 15) * 8;      // 8 channels = 8 fp8 bytes
#pragma unroll
        for (int pair = 0; pair < 2; ++pair) {
            const int iA = node0 + (pair * 2 + 0) * 16 + slot;
            const int iB = node0 + (pair * 2 + 1) * 16 + slot;
            f32x2 fA[4], fB[4];
            set8_fp8v(*(const uint2*)(hin8 + (size_t)iA * 128 + c0), fA);   // self A
            set8_fp8v(*(const uint2*)(hin8 + (size_t)iB * 128 + c0), fB);   // self B
            const int eA = g_row_start[iA], e1A = g_row_start[iA + 1];
            const int eB = g_row_start[iB], e1B = g_row_start[iB + 1];
            // r27: clamp index = node's OWN last edge (deg-0 safe via max
            // with e; final min keeps it in-bounds). Exhausted rounds re-read
            // a just-fetched row -> L2 hit, no random garbage traffic.
            const int emA = min(max(e1A - 1, eA), N_EDGES - 1);
            const int emB = min(max(e1B - 1, eB), N_EDGES - 1);
            const int dmax = max(e1A - eA, e1B - eB);
            for (int done = 0; done < dmax; done += 4) {
                const int bA = eA + done, bB = eB + done;
                int sA0 = g_csr_src[min(bA,     emA)];
                int sA1 = g_csr_src[min(bA + 1, emA)];
                int sA2 = g_csr_src[min(bA + 2, emA)];
                int sA3 = g_csr_src[min(bA + 3, emA)];
                int sB0 = g_csr_src[min(bB,     emB)];
                int sB1 = g_csr_src[min(bB + 1, emB)];
                int sB2 = g_csr_src[min(bB + 2, emB)];
                int sB3 = g_csr_src[min(bB + 3, emB)];
                uint2 rA0 = *(const uint2*)(hin8 + (size_t)sA0 * 128 + c0);
                uint2 rA1 = *(const uint2*)(hin8 + (size_t)sA1 * 128 + c0);
                uint2 rA2 = *(const uint2*)(hin8 + (size_t)sA2 * 128 + c0);
                uint2 rA3 = *(const uint2*)(hin8 + (size_t)sA3 * 128 + c0);
                uint2 rB0 = *(const uint2*)(hin8 + (size_t)sB0 * 128 + c0);
                uint2 rB1 = *(const uint2*)(hin8 + (size_t)sB1 * 128 + c0);
                uint2 rB2 = *(const uint2*)(hin8 + (size_t)sB2 * 128 + c0);
                uint2 rB3 = *(const uint2*)(hin8 + (size_t)sB3 * 128 + c0);
                __builtin_amdgcn_sched_barrier(0);   // keep the 8 row loads clustered
                if (bA     >= e1A) { rA0.x = 0u; rA0.y = 0u; }   // fp8 0x00 == 0.0
                if (bA + 1 >= e1A) { rA1.x = 0u; rA1.y = 0u; }
                if (bA + 2 >= e1A) { rA2.x = 0u; rA2.y = 0u; }
                if (bA + 3 >= e1A) { rA3.x = 0u; rA3.y = 0u; }
                if (bB     >= e1B) { rB0.x = 0u; rB0.y = 0u; }
                if (bB + 1 >= e1B) { rB1.x = 0u; rB1.y = 0u; }
                if (bB + 2 >= e1B) { rB2.x = 0u; rB2.y = 0u; }
                if (bB + 3 >= e1B) { rB3.x = 0u; rB3.y = 0u; }
                add8_fp8v(rA0, fA); add8_fp8v(rA1, fA); add8_fp8v(rA2, fA); add8_fp8v(rA3, fA);
                add8_fp8v(rB0, fB); add8_fp8v(rB1, fB); add8_fp8v(rB2, fB); add8_fp8v(rB3, fB);
            }
            *(uint4*)(&As[(pair * 2 + 0) * 16 + slot][c0]) = pack8v(fA);
            *(uint4*)(&As[(pair * 2 + 1) * 16 + slot][c0]) = pack8v(fB);
        }
    }

    const int wv = tid >> 6;        // wave 0..3 -> cols [wv*32, wv*32+32)
    const int lane = tid & 63;
    const int lm = lane & 15;
    const int lq = lane >> 4;

    __syncthreads();

    // ---- MFMA: kb-outer so only 2 B-frags live at a time ----
    f32x4 acc[4][2];
#pragma unroll
    for (int mt = 0; mt < 4; ++mt)
#pragma unroll
        for (int nt = 0; nt < 2; ++nt) acc[mt][nt] = (f32x4){0.f, 0.f, 0.f, 0.f};

#pragma unroll
    for (int kb = 0; kb < 4; ++kb) {
        f16x8 bq[2];
#pragma unroll
        for (int nt = 0; nt < 2; ++nt)
            __builtin_memcpy(&bq[nt],
                             WtG + (size_t)(wv * 32 + nt * 16 + lm) * 128 + kb * 32 + lq * 8, 16);
#pragma unroll
        for (int mt = 0; mt < 4; ++mt) {
            f16x8 afr;
            __builtin_memcpy(&afr, &As[mt * 16 + lm][kb * 32 + lq * 8], 16);
#pragma unroll
            for (int nt = 0; nt < 2; ++nt)
                acc[mt][nt] = __builtin_amdgcn_mfma_f32_16x16x32_f16(afr, bq[nt], acc[mt][nt], 0, 0, 0);
        }
    }

    float4 dv4[4];
#pragma unroll
    for (int mt = 0; mt < 4; ++mt)
        dv4[mt] = *(const float4*)(g_dinv + node0 + mt * 16 + lq * 4);

    if (OUTMODE == 2 && tid < 64) bsh[tid] = batch[node0 + tid];

    __syncthreads();

    // ---- epilogue: BN/ReLU, stage C (fp16) in As ----
#pragma unroll
    for (int nt = 0; nt < 2; ++nt) {
        int c = wv * 32 + nt * 16 + lm;
        float s = g[c] * rsqrtf(rv[c] + BN_EPS);
        float o = fmaf(b[c] - rm[c], s, bt[c]);
#pragma unroll
        for (int mt = 0; mt < 4; ++mt) {
            float dvr[4] = {dv4[mt].x, dv4[mt].y, dv4[mt].z, dv4[mt].w};
#pragma unroll
            for (int r = 0; r < 4; ++r) {
                float pm = PRE ? dvr[r] : 1.0f;
                float y = fmaxf(fmaf(acc[mt][nt][r] * dvr[r], s, o), 0.f) * pm;
                As[mt * 16 + lq * 4 + r][c] = __float2half_rn(y);
            }
        }
    }
    __syncthreads();

    if (OUTMODE == 1) {
#pragma unroll
        for (int i = 0; i < 2; ++i) {
            int u = tid + i * 256;                 // 0..511
            int row = u >> 3, cb = (u & 7) * 16;   // 16 cols/thread
            float fa[8], fb[8];
            set8(*(const uint4*)(&As[row][cb]), fa);
            set8(*(const uint4*)(&As[row][cb + 8]), fb);
            uint2 pa = pack8_fp8(fa), pb = pack8_fp8(fb);
            uint4 v; v.x = pa.x; v.y = pa.y; v.z = pb.x; v.w = pb.y;
            *(uint4*)(hout8 + (size_t)(node0 + row) * 128 + cb) = v;
        }
    } else {
        // fused segment-sum pooling (batch sorted): run-length sum by graph.
        const int c = tid & 127;
        const int r0 = (tid >> 7) * 32;
        float accp = 0.f;
        int g0 = bsh[r0];
        for (int row = r0; row < r0 + 32; ++row) {
            int gg = bsh[row];
            if (gg != g0) {
                atomicAdd(&g_agg7[(size_t)g0 * 128 + c], accp);
                accp = 0.f; g0 = gg;
            }
            accp += __half2float(As[row][c]);
        }
        atomicAdd(&g_agg7[(size_t)g0 * 128 + c], accp);
    }
}

// ---------------- fused head: hidden in LDS, logits out (1 launch) --------

__global__ __launch_bounds__(256) void k_head(const float* __restrict__ Wc1,
                                              const float* __restrict__ bc1,
                                              const float* __restrict__ Wc2,
                                              const float* __restrict__ bc2,
                                              float* __restrict__ out) {
    __shared__ float hsh[4][64];
    const int g4 = blockIdx.x * 4;              // 4 graphs per block
    const int gi = g4 + (threadIdx.x >> 6);
    const int c = threadIdx.x & 63;
    const float* pooled = g_agg7;
    int cnt = g_gstart[gi + 1] - g_gstart[gi];
    float inv = 1.0f / (float)max(cnt, 1);
    float z = 0.f;
#pragma unroll 8
    for (int k = 0; k < 128; ++k) z = fmaf(pooled[(size_t)gi * 128 + k], Wc1[k * 64 + c], z);
    hsh[threadIdx.x >> 6][c] = fmaxf(fmaf(z, inv, bc1[c]), 0.f);
    __syncthreads();
    if (threadIdx.x < 4) {
        float zz = bc2[0];
#pragma unroll 8
        for (int k = 0; k < 64; ++k) zz = fmaf(hsh[threadIdx.x][k], Wc2[k], zz);
        out[g4 + threadIdx.x] = zz;
    }
}

// ---------------- launch ----------------

extern "C" void kernel_launch(void* const* d_in, const int* in_sizes, int n_in,
                              void* d_out, int out_size, void* d_ws, size_t ws_size,
                              hipStream_t stream) {
    const float* x     = (const float*)d_in[0];
    const int*   ei    = (const int*)d_in[1];
    const int*   batch = (const int*)d_in[2];
    const float* W1 = (const float*)d_in[3];
    const float* b1 = (const float*)d_in[4];
    const float* g1 = (const float*)d_in[5];
    const float* bt1= (const float*)d_in[6];
    const float* rm1= (const float*)d_in[7];
    const float* rv1= (const float*)d_in[8];
    const float* W2 = (const float*)d_in[9];
    const float* b2 = (const float*)d_in[10];
    const float* g2 = (const float*)d_in[11];
    const float* bt2= (const float*)d_in[12];
    const float* rm2= (const float*)d_in[13];
    const float* rv2= (const float*)d_in[14];
    const float* W3 = (const float*)d_in[15];
    const float* b3 = (const float*)d_in[16];
    const float* g3 = (const float*)d_in[17];
    const float* bt3= (const float*)d_in[18];
    const float* rm3= (const float*)d_in[19];
    const float* rv3= (const float*)d_in[20];
    const float* Wc1= (const float*)d_in[21];
    const float* bc1= (const float*)d_in[22];
    const float* Wc2= (const float*)d_in[23];
    const float* bc2= (const float*)d_in[24];
    float* outp = (float*)d_out;
    (void)d_ws; (void)ws_size; (void)n_in; (void)in_sizes;

    const int* srcp = ei;
    const int* dstp = ei + N_EDGES;

    // prep: zero rowcnt + wt1/wt2/wt3 transposes
    k_prep<<<4051, 256, 0, stream>>>(W1, W2, W3);

    // CSR build (by dst); scan1 also emits dinv + px fp16x8
    k_hist<<<(N_EDGES + 255) / 256, 256, 0, stream>>>(dstp);
    k_scan1<<<NBLK1, 256, 0, stream>>>(x);
    k_scan2<<<1, 256, 0, stream>>>();
    k_scan3<<<NBLK1, 256, 0, stream>>>();
    k_scatter<<<(N_EDGES + 255) / 256, 256, 0, stream>>>(srcp, dstp);

    // graph boundaries + pooled-sum zeroing (1 launch)
    k_gz<<<4225, 256, 0, stream>>>(batch);

    // layer 1: fused gather+MFMA lin1+BN/ReLU -> q1 fp8
    k_l1_fused<<<N_NODES / 64, 256, 0, stream>>>(b1, g1, bt1, rm1, rv1);

    // layers 2,3: fused gather + MFMA GEMM
    k_agg_gemm<true,  true,  0, 1><<<N_NODES / 64, 256, 0, stream>>>(b2, g2, bt2, rm2, rv2, batch);
    k_agg_gemm<false, false, 1, 2><<<N_NODES / 64, 256, 0, stream>>>(b3, g3, bt3, rm3, rv3, batch);

    // fused head MLP
    k_head<<<N_GRAPHS / 4, 256, 0, stream>>>(Wc1, bc1, Wc2, bc2, outp);
}

// Round 11
// 910.091 us; speedup vs baseline: 1.3121x; 1.1666x over previous
//
#include <hip/hip_runtime.h>
#include <hip/hip_fp16.h>

#define N_NODES 1000000
#define N_EDGES 4000000
#define N_GRAPHS 32768
#define BN_EPS 1e-5f
#define NBLK1 3907   // ceil(N_NODES/256)
#define NB 256       // csr-build buckets (dst >> 12)
#define BKT_SHIFT 12
#define EPB 2048     // edges per bucket-scatter block
#define NSCAT 1954   // ceil(N_EDGES / EPB)
#define CAPB 32      // per-block per-bucket LDS list capacity

typedef _Float16 f16;
typedef f16   f16x8 __attribute__((ext_vector_type(8)));
typedef float f32x4 __attribute__((ext_vector_type(4)));
typedef float f32x2 __attribute__((ext_vector_type(2)));

// ---------------------------------------------------------------------------
// Static device-global scratch.
// r21 fp8 gather rows. r22 fused pooling. r23 l1 fused. r25 launch fusion.
// r26/r27 2-list interleaved gather with own-last-edge clamp.
// r28: CSR build reworked — k_scatter's 255 MB WRITE (4M scattered 4B
// writes -> full-line dirties) + k_hist's 4M random atomics replaced by a
// 2-phase bucket pipeline (LDS histograms, chunked segment writes,
// per-bucket L2-local degree count + csr scatter; zero global-random atomics).
// ---------------------------------------------------------------------------
__device__ __half g_hA[128000000];      // 256 MB: q1 fp8 (first 128 MB)
__device__ __half g_hB[128000000];      // 256 MB: px fp16x8 (16 MB) -> h2 fp8 (128 MB)
__device__ float  g_agg7[8400000];      //  33.6 MB: pooled SUMS
__device__ float  g_dinv[N_NODES];
__device__ int    g_rowcnt[N_NODES];
__device__ int    g_row_start[N_NODES + 1];
__device__ int    g_csr_src[N_EDGES];
__device__ unsigned g_pairs[N_EDGES];   // 16 MB packed (src<<12 | dst&4095)
__device__ int    g_part[NBLK1];
__device__ int    g_gstart[N_GRAPHS + 1];
__device__ int    g_bcnt[NB];
__device__ int    g_bstart[NB + 1];
__device__ int    g_bcur[NB];
__device__ __align__(16) __half g_wt1[4096];    // W1^T fp16 [n][k], K padded to 32
__device__ __align__(16) __half g_wt2[16384];   // W2^T fp16 [n][k]
__device__ __align__(16) __half g_wt3[16384];   // W3^T fp16 [n][k]

// ---------------- fp16 helpers ----------------

__device__ __forceinline__ void set8(uint4 raw, float f[8]) {
    __half2 h; float2 a;
    __builtin_memcpy(&h, &raw.x, 4); a = __half22float2(h); f[0] = a.x; f[1] = a.y;
    __builtin_memcpy(&h, &raw.y, 4); a = __half22float2(h); f[2] = a.x; f[3] = a.y;
    __builtin_memcpy(&h, &raw.z, 4); a = __half22float2(h); f[4] = a.x; f[5] = a.y;
    __builtin_memcpy(&h, &raw.w, 4); a = __half22float2(h); f[6] = a.x; f[7] = a.y;
}
__device__ __forceinline__ uint4 pack8(const float f[8]) {
    __half2 h0 = __floats2half2_rn(f[0], f[1]);
    __half2 h1 = __floats2half2_rn(f[2], f[3]);
    __half2 h2 = __floats2half2_rn(f[4], f[5]);
    __half2 h3 = __floats2half2_rn(f[6], f[7]);
    uint4 raw;
    __builtin_memcpy(&raw.x, &h0, 4);
    __builtin_memcpy(&raw.y, &h1, 4);
    __builtin_memcpy(&raw.z, &h2, 4);
    __builtin_memcpy(&raw.w, &h3, 4);
    return raw;
}
__device__ __forceinline__ f32x2 cvt2h(unsigned raw) {
    __half2 h; __builtin_memcpy(&h, &raw, 4);
    float2 a = __half22float2(h);
    f32x2 r; r.x = a.x; r.y = a.y; return r;
}

// ---------------- fp8 e4m3 helpers (vector f32x2 accumulators) ----------------

__device__ __forceinline__ void set8_fp8v(uint2 raw, f32x2 f[4]) {
    f[0] = __builtin_amdgcn_cvt_pk_f32_fp8(raw.x, false);
    f[1] = __builtin_amdgcn_cvt_pk_f32_fp8(raw.x, true);
    f[2] = __builtin_amdgcn_cvt_pk_f32_fp8(raw.y, false);
    f[3] = __builtin_amdgcn_cvt_pk_f32_fp8(raw.y, true);
}
__device__ __forceinline__ void add8_fp8v(uint2 raw, f32x2 f[4]) {
    f[0] += __builtin_amdgcn_cvt_pk_f32_fp8(raw.x, false);   // v_pk_add_f32
    f[1] += __builtin_amdgcn_cvt_pk_f32_fp8(raw.x, true);
    f[2] += __builtin_amdgcn_cvt_pk_f32_fp8(raw.y, false);
    f[3] += __builtin_amdgcn_cvt_pk_f32_fp8(raw.y, true);
}
__device__ __forceinline__ uint4 pack8v(const f32x2 f[4]) {
    __half2 h0 = __floats2half2_rn(f[0].x, f[0].y);
    __half2 h1 = __floats2half2_rn(f[1].x, f[1].y);
    __half2 h2 = __floats2half2_rn(f[2].x, f[2].y);
    __half2 h3 = __floats2half2_rn(f[3].x, f[3].y);
    uint4 raw;
    __builtin_memcpy(&raw.x, &h0, 4);
    __builtin_memcpy(&raw.y, &h1, 4);
    __builtin_memcpy(&raw.z, &h2, 4);
    __builtin_memcpy(&raw.w, &h3, 4);
    return raw;
}
__device__ __forceinline__ uint2 pack8_fp8(const float f[8]) {
    int lo = 0, hi = 0;
    lo = __builtin_amdgcn_cvt_pk_fp8_f32(f[0], f[1], lo, false);
    lo = __builtin_amdgcn_cvt_pk_fp8_f32(f[2], f[3], lo, true);
    hi = __builtin_amdgcn_cvt_pk_fp8_f32(f[4], f[5], hi, false);
    hi = __builtin_amdgcn_cvt_pk_fp8_f32(f[6], f[7], hi, true);
    uint2 r; r.x = (unsigned)lo; r.y = (unsigned)hi; return r;
}

// ---------------- prep: zero rowcnt/bcnt + weight transposes (1 launch) ----

__global__ __launch_bounds__(256) void k_prep(const float* __restrict__ W1,
                                              const float* __restrict__ W2,
                                              const float* __restrict__ W3) {
    int t = blockIdx.x * 256 + threadIdx.x;
    if (t < N_NODES) { g_rowcnt[t] = 0; return; }
    int u = t - N_NODES;
    if (u < 32768) {                       // W2/W3 -> fp16 transposed
        int sel = u >> 14, v = u & 16383;
        int n = v & 127, k = v >> 7;
        (sel ? g_wt3 : g_wt2)[n * 128 + k] = __float2half_rn((sel ? W3 : W2)[k * 128 + n]);
        return;
    }
    u -= 32768;
    if (u < 4096) {                        // W1^T fp16 [128][32], k>=7 zero
        int n = u & 127, k = u >> 7;
        g_wt1[n * 32 + k] = (k < 7) ? __float2half_rn(W1[k * 128 + n]) : __float2half_rn(0.f);
        return;
    }
    u -= 4096;
    if (u < NB) g_bcnt[u] = 0;
}

// ---------------- bucketed CSR build (r28) ----------------

// bucket histogram: LDS-reduced, 256 global atomics/block (low contention)
__global__ __launch_bounds__(256) void k_bhist(const int* __restrict__ dst) {
    __shared__ int h[NB];
    h[threadIdx.x] = 0;
    __syncthreads();
    int base = blockIdx.x * EPB;
#pragma unroll
    for (int k = 0; k < 8; ++k) {
        int e = base + k * 256 + threadIdx.x;
        if (e < N_EDGES) atomicAdd(&h[((unsigned)dst[e]) >> BKT_SHIFT], 1);
    }
    __syncthreads();
    int c = h[threadIdx.x];
    if (c) atomicAdd(&g_bcnt[threadIdx.x], c);
}

// scan bucket counts -> segment starts; init write cursors
__global__ __launch_bounds__(256) void k_bscan() {
    __shared__ int sh[256];
    int v = g_bcnt[threadIdx.x];
    sh[threadIdx.x] = v;
    __syncthreads();
#pragma unroll
    for (int off = 1; off < 256; off <<= 1) {
        int t = (threadIdx.x >= off) ? sh[threadIdx.x - off] : 0;
        __syncthreads();
        sh[threadIdx.x] += t;
        __syncthreads();
    }
    int excl = sh[threadIdx.x] - v;
    g_bstart[threadIdx.x] = excl;
    g_bcur[threadIdx.x] = excl;
    if (threadIdx.x == 255) g_bstart[NB] = N_EDGES;
}

// bin edges into bucket segments: LDS lists + chunked reservations
__global__ __launch_bounds__(256) void k_bscatter(const int* __restrict__ src,
                                                  const int* __restrict__ dst) {
    __shared__ int lcnt[NB];
    __shared__ unsigned llist[NB][CAPB];     // 32 KB
    lcnt[threadIdx.x] = 0;
    __syncthreads();
    int base = blockIdx.x * EPB;
#pragma unroll
    for (int k = 0; k < 8; ++k) {
        int e = base + k * 256 + threadIdx.x;
        if (e < N_EDGES) {
            unsigned d = (unsigned)dst[e];
            unsigned p = (((unsigned)src[e]) << BKT_SHIFT) | (d & 4095u);
            int b = (int)(d >> BKT_SHIFT);
            int slot = atomicAdd(&lcnt[b], 1);
            if (slot < CAPB) llist[b][slot] = p;
            else {                               // rare overflow: direct reserve
                int gpos = atomicAdd(&g_bcur[b], 1);
                g_pairs[gpos] = p;
            }
        }
    }
    __syncthreads();
    int c = min(lcnt[threadIdx.x], CAPB);
    if (c > 0) {
        int gbase = atomicAdd(&g_bcur[threadIdx.x], c);
        for (int i = 0; i < c; ++i) g_pairs[gbase + i] = llist[threadIdx.x][i];
    }
}

// per-bucket degree count (LDS counters, no global atomics), coalesced out
__global__ __launch_bounds__(256) void k_bdeg() {
    __shared__ int cnt[4096];                // 16 KB
    const int b = blockIdx.x;
    for (int j = threadIdx.x; j < 4096; j += 256) cnt[j] = 0;
    __syncthreads();
    const int s0 = g_bstart[b], s1 = g_bstart[b + 1];
    for (int i = s0 + threadIdx.x; i < s1; i += 256)
        atomicAdd(&cnt[g_pairs[i] & 4095u], 1);
    __syncthreads();
    const int n0 = b << BKT_SHIFT;
    for (int j = threadIdx.x; j < 4096; j += 256)
        if (n0 + j < N_NODES) g_rowcnt[n0 + j] = cnt[j];
}

// per-bucket csr scatter: all writes land in this bucket's ~62 KB region
// from ONE block -> one CU's L2 -> full-line writebacks (vs 255 MB before)
__global__ __launch_bounds__(256) void k_bcsr() {
    __shared__ int cnt[4096];
    const int b = blockIdx.x;
    for (int j = threadIdx.x; j < 4096; j += 256) cnt[j] = 0;
    __syncthreads();
    const int s0 = g_bstart[b], s1 = g_bstart[b + 1];
    const int n0 = b << BKT_SHIFT;
    for (int i = s0 + threadIdx.x; i < s1; i += 256) {
        unsigned p = g_pairs[i];
        int dl = (int)(p & 4095u);
        int off = atomicAdd(&cnt[dl], 1);
        int pos = g_row_start[n0 + dl] + off;
        g_csr_src[pos] = (int)(p >> BKT_SHIFT);
    }
}

// scan1 also computes dinv AND px (fp16x8 row of dinv*x)
__global__ __launch_bounds__(256) void k_scan1(const float* __restrict__ x) {
    __shared__ int sh[256];
    int i = blockIdx.x * 256 + threadIdx.x;
    int v = (i < N_NODES) ? g_rowcnt[i] : 0;
    if (i < N_NODES) {
        float w = rsqrtf((float)(1 + v));   // +1 self-loop
        g_dinv[i] = w;
        float vv[8];
#pragma unroll
        for (int k = 0; k < 7; ++k) vv[k] = x[i * 7 + k] * w;
        vv[7] = 0.f;
        *(uint4*)(g_hB + (size_t)i * 8) = pack8(vv);
    }
    sh[threadIdx.x] = v;
    __syncthreads();
#pragma unroll
    for (int off = 1; off < 256; off <<= 1) {
        int t = (threadIdx.x >= off) ? sh[threadIdx.x - off] : 0;
        __syncthreads();
        sh[threadIdx.x] += t;
        __syncthreads();
    }
    int incl = sh[threadIdx.x];
    if (i < N_NODES) g_row_start[i] = incl - v;
    if (threadIdx.x == 255) g_part[blockIdx.x] = incl;
}

__global__ __launch_bounds__(256) void k_scan2() {
    __shared__ int sh[256];
    int base = threadIdx.x * 16;
    int local[16];
    int s = 0;
#pragma unroll
    for (int k = 0; k < 16; ++k) {
        local[k] = (base + k < NBLK1) ? g_part[base + k] : 0;
        s += local[k];
    }
    sh[threadIdx.x] = s;
    __syncthreads();
#pragma unroll
    for (int off = 1; off < 256; off <<= 1) {
        int t = (threadIdx.x >= off) ? sh[threadIdx.x - off] : 0;
        __syncthreads();
        sh[threadIdx.x] += t;
        __syncthreads();
    }
    int carry = sh[threadIdx.x] - s;
#pragma unroll
    for (int k = 0; k < 16; ++k) {
        if (base + k < NBLK1) {
            int t = local[k];
            g_part[base + k] = carry;
            carry += t;
        }
    }
}

__global__ __launch_bounds__(256) void k_scan3() {
    int i = blockIdx.x * 256 + threadIdx.x;
    if (i < N_NODES) g_row_start[i] += g_part[blockIdx.x];
    if (i == 0) g_row_start[N_NODES] = N_EDGES;
}

// ---------------- gstart + pooled zero (1 launch) ----------------

__global__ __launch_bounds__(256) void k_gz(const int* __restrict__ batch) {
    int blk = blockIdx.x;
    if (blk < 4096) {                      // zero pooled sums (16.78 MB)
        int t = blk * 256 + threadIdx.x;
        *(float4*)(g_agg7 + (size_t)t * 4) = make_float4(0.f, 0.f, 0.f, 0.f);
        return;
    }
    int gidx = (blk - 4096) * 256 + threadIdx.x;
    if (gidx > N_GRAPHS) return;
    int lo = 0, hi = N_NODES;
    while (lo < hi) {
        int mid = (lo + hi) >> 1;
        if (batch[mid] < gidx) lo = mid + 1; else hi = mid;
    }
    g_gstart[gidx] = lo;
}

// ---------------- fused layer-1: gather(px) + MFMA lin1 + BN/ReLU -> q1 fp8

__global__ __launch_bounds__(256, 7) void k_l1_fused(const float* __restrict__ b,
                                                     const float* __restrict__ g,
                                                     const float* __restrict__ bt,
                                                     const float* __restrict__ rm,
                                                     const float* __restrict__ rv) {
    const __half* __restrict__ px = g_hB;
    unsigned char* __restrict__ q1 = (unsigned char*)g_hA;

    __shared__ __half As[64][152];          // 19,456 B
    const int tid = threadIdx.x;
    const int node0 = blockIdx.x * 64;

    // ---- gather: 4 threads/node, one pass ----
    {
        const int slot = tid >> 2;          // 0..63
        const int q = tid & 3;              // channel pair
        int i = node0 + slot;
        f32x2 f = cvt2h(*(const unsigned*)(px + (size_t)i * 8 + q * 2));   // self
        int e = g_row_start[i], e1 = g_row_start[i + 1];
        for (; e + 4 <= e1; e += 4) {
            int s0 = g_csr_src[e + 0], s1 = g_csr_src[e + 1];
            int s2 = g_csr_src[e + 2], s3 = g_csr_src[e + 3];
            unsigned r0 = *(const unsigned*)(px + (size_t)s0 * 8 + q * 2);
            unsigned r1 = *(const unsigned*)(px + (size_t)s1 * 8 + q * 2);
            unsigned r2 = *(const unsigned*)(px + (size_t)s2 * 8 + q * 2);
            unsigned r3 = *(const unsigned*)(px + (size_t)s3 * 8 + q * 2);
            f += cvt2h(r0); f += cvt2h(r1); f += cvt2h(r2); f += cvt2h(r3);
        }
        for (; e < e1; ++e)
            f += cvt2h(*(const unsigned*)(px + (size_t)g_csr_src[e] * 8 + q * 2));
        __half2 hv = __floats2half2_rn(f.x, f.y);
        unsigned u; __builtin_memcpy(&u, &hv, 4);
        *(unsigned*)(&As[slot][q * 2]) = u;
        uint4 z; z.x = 0; z.y = 0; z.z = 0; z.w = 0;
        *(uint4*)(&As[slot][8 + q * 8]) = z;    // zero K pad halves 8..39
    }

    const int wv = tid >> 6;        // wave 0..3 -> cols [wv*32, wv*32+32)
    const int lane = tid & 63;
    const int lm = lane & 15;
    const int lq = lane >> 4;

    __syncthreads();

    // ---- MFMA: K=32 (single kb) ----
    f32x4 acc[4][2];
#pragma unroll
    for (int mt = 0; mt < 4; ++mt)
#pragma unroll
        for (int nt = 0; nt < 2; ++nt) acc[mt][nt] = (f32x4){0.f, 0.f, 0.f, 0.f};

    f16x8 bq[2];
#pragma unroll
    for (int nt = 0; nt < 2; ++nt)
        __builtin_memcpy(&bq[nt], g_wt1 + (size_t)(wv * 32 + nt * 16 + lm) * 32 + lq * 8, 16);
#pragma unroll
    for (int mt = 0; mt < 4; ++mt) {
        f16x8 afr;
        __builtin_memcpy(&afr, &As[mt * 16 + lm][lq * 8], 16);
#pragma unroll
        for (int nt = 0; nt < 2; ++nt)
            acc[mt][nt] = __builtin_amdgcn_mfma_f32_16x16x32_f16(afr, bq[nt], acc[mt][nt], 0, 0, 0);
    }

    float4 dv4[4];
#pragma unroll
    for (int mt = 0; mt < 4; ++mt)
        dv4[mt] = *(const float4*)(g_dinv + node0 + mt * 16 + lq * 4);

    __syncthreads();   // all As gather reads done before C staging

    // ---- epilogue: BN/ReLU (PRE), stage C fp16 in As ----
#pragma unroll
    for (int nt = 0; nt < 2; ++nt) {
        int c = wv * 32 + nt * 16 + lm;
        float s = g[c] * rsqrtf(rv[c] + BN_EPS);
        float o = fmaf(b[c] - rm[c], s, bt[c]);
#pragma unroll
        for (int mt = 0; mt < 4; ++mt) {
            float dvr[4] = {dv4[mt].x, dv4[mt].y, dv4[mt].z, dv4[mt].w};
#pragma unroll
            for (int r = 0; r < 4; ++r) {
                float y = fmaxf(fmaf(acc[mt][nt][r] * dvr[r], s, o), 0.f) * dvr[r];
                As[mt * 16 + lq * 4 + r][c] = __float2half_rn(y);
            }
        }
    }
    __syncthreads();
#pragma unroll
    for (int i = 0; i < 2; ++i) {
        int u = tid + i * 256;                 // 0..511
        int row = u >> 3, cb = (u & 7) * 16;   // 16 cols/thread
        float fa[8], fb[8];
        set8(*(const uint4*)(&As[row][cb]), fa);
        set8(*(const uint4*)(&As[row][cb + 8]), fb);
        uint2 pa = pack8_fp8(fa), pb = pack8_fp8(fb);
        uint4 v; v.x = pa.x; v.y = pa.y; v.z = pb.x; v.w = pb.y;
        *(uint4*)(q1 + (size_t)(node0 + row) * 128 + cb) = v;
    }
}

// ---------------- fused CSR-gather + MFMA GEMM + BN + ReLU (layers 2,3) ----
// LEDGER:
//  r18 interleave (fp16 era) -> spills. r19 nt stores -> WRITE x5.
//  r19b bounds(256,8) -> thrash. r21 fp8 rows 374->277. r22 fused pooling
//  277->237. r24 degree-sort REGRESSED. r26 2-list interleave 237->219
//  (clamp bug FETCH 568). r27 own-last-edge clamp -> FETCH fixed, scatter
//  became #1. r28 bucketed CSR build (this file).
// OUTMODE: 1 = fp8 row store (layer 2), 2 = fused pool (layer 3).

template <bool PRE, bool ATOB, int WSEL, int OUTMODE>
__global__ __launch_bounds__(256, 7) void k_agg_gemm(const float* __restrict__ b,
                                                     const float* __restrict__ g,
                                                     const float* __restrict__ bt,
                                                     const float* __restrict__ rm,
                                                     const float* __restrict__ rv,
                                                     const int* __restrict__ batch) {
    const unsigned char* __restrict__ hin8 =
        (const unsigned char*)(ATOB ? g_hA : g_hB);          // fp8 rows, 128 B
    unsigned char* __restrict__ hout8 =
        (unsigned char*)(ATOB ? g_hB : g_hA);                // fp8 rows, 128 B
    const __half* __restrict__ WtG = (WSEL == 0) ? g_wt2 : g_wt3;

    __shared__ __half As[64][152];          // 19,456 B
    __shared__ int bsh[64];
    const int tid = threadIdx.x;
    const int node0 = blockIdx.x * 64;

    // ---- gather: 2-list interleave, clamped-to-own-last-edge batches ----
    {
        const int slot = tid >> 4;          // 0..15
        const int c0 = (tid & 15) * 8;      // 8 channels = 8 fp8 bytes
#pragma unroll
        for (int pair = 0; pair < 2; ++pair) {
            const int iA = node0 + (pair * 2 + 0) * 16 + slot;
            const int iB = node0 + (pair * 2 + 1) * 16 + slot;
            f32x2 fA[4], fB[4];
            set8_fp8v(*(const uint2*)(hin8 + (size_t)iA * 128 + c0), fA);   // self A
            set8_fp8v(*(const uint2*)(hin8 + (size_t)iB * 128 + c0), fB);   // self B
            const int eA = g_row_start[iA], e1A = g_row_start[iA + 1];
            const int eB = g_row_start[iB], e1B = g_row_start[iB + 1];
            const int emA = min(max(e1A - 1, eA), N_EDGES - 1);
            const int emB = min(max(e1B - 1, eB), N_EDGES - 1);
            const int dmax = max(e1A - eA, e1B - eB);
            for (int done = 0; done < dmax; done += 4) {
                const int bA = eA + done, bB = eB + done;
                int sA0 = g_csr_src[min(bA,     emA)];
                int sA1 = g_csr_src[min(bA + 1, emA)];
                int sA2 = g_csr_src[min(bA + 2, emA)];
                int sA3 = g_csr_src[min(bA + 3, emA)];
                int sB0 = g_csr_src[min(bB,     emB)];
                int sB1 = g_csr_src[min(bB + 1, emB)];
                int sB2 = g_csr_src[min(bB + 2, emB)];
                int sB3 = g_csr_src[min(bB + 3, emB)];
                uint2 rA0 = *(const uint2*)(hin8 + (size_t)sA0 * 128 + c0);
                uint2 rA1 = *(const uint2*)(hin8 + (size_t)sA1 * 128 + c0);
                uint2 rA2 = *(const uint2*)(hin8 + (size_t)sA2 * 128 + c0);
                uint2 rA3 = *(const uint2*)(hin8 + (size_t)sA3 * 128 + c0);
                uint2 rB0 = *(const uint2*)(hin8 + (size_t)sB0 * 128 + c0);
                uint2 rB1 = *(const uint2*)(hin8 + (size_t)sB1 * 128 + c0);
                uint2 rB2 = *(const uint2*)(hin8 + (size_t)sB2 * 128 + c0);
                uint2 rB3 = *(const uint2*)(hin8 + (size_t)sB3 * 128 + c0);
                __builtin_amdgcn_sched_barrier(0);   // keep the 8 row loads clustered
                if (bA     >= e1A) { rA0.x = 0u; rA0.y = 0u; }   // fp8 0x00 == 0.0
                if (bA + 1 >= e1A) { rA1.x = 0u; rA1.y = 0u; }
                if (bA + 2 >= e1A) { rA2.x = 0u; rA2.y = 0u; }
                if (bA + 3 >= e1A) { rA3.x = 0u; rA3.y = 0u; }
                if (bB     >= e1B) { rB0.x = 0u; rB0.y = 0u; }
                if (bB + 1 >= e1B) { rB1.x = 0u; rB1.y = 0u; }
                if (bB + 2 >= e1B) { rB2.x = 0u; rB2.y = 0u; }
                if (bB + 3 >= e1B) { rB3.x = 0u; rB3.y = 0u; }
                add8_fp8v(rA0, fA); add8_fp8v(rA1, fA); add8_fp8v(rA2, fA); add8_fp8v(rA3, fA);
                add8_fp8v(rB0, fB); add8_fp8v(rB1, fB); add8_fp8v(rB2, fB); add8_fp8v(rB3, fB);
            }
            *(uint4*)(&As[(pair * 2 + 0) * 16 + slot][c0]) = pack8v(fA);
            *(uint4*)(&As[(pair * 2 + 1) * 16 + slot][c0]) = pack8v(fB);
        }
    }

    const int wv = tid >> 6;        // wave 0..3 -> cols [wv*32, wv*32+32)
    const int lane = tid & 63;
    const int lm = lane & 15;
    const int lq = lane >> 4;

    __syncthreads();

    // ---- MFMA: kb-outer so only 2 B-frags live at a time ----
    f32x4 acc[4][2];
#pragma unroll
    for (int mt = 0; mt < 4; ++mt)
#pragma unroll
        for (int nt = 0; nt < 2; ++nt) acc[mt][nt] = (f32x4){0.f, 0.f, 0.f, 0.f};

#pragma unroll
    for (int kb = 0; kb < 4; ++kb) {
        f16x8 bq[2];
#pragma unroll
        for (int nt = 0; nt < 2; ++nt)
            __builtin_memcpy(&bq[nt],
                             WtG + (size_t)(wv * 32 + nt * 16 + lm) * 128 + kb * 32 + lq * 8, 16);
#pragma unroll
        for (int mt = 0; mt < 4; ++mt) {
            f16x8 afr;
            __builtin_memcpy(&afr, &As[mt * 16 + lm][kb * 32 + lq * 8], 16);
#pragma unroll
            for (int nt = 0; nt < 2; ++nt)
                acc[mt][nt] = __builtin_amdgcn_mfma_f32_16x16x32_f16(afr, bq[nt], acc[mt][nt], 0, 0, 0);
        }
    }

    float4 dv4[4];
#pragma unroll
    for (int mt = 0; mt < 4; ++mt)
        dv4[mt] = *(const float4*)(g_dinv + node0 + mt * 16 + lq * 4);

    if (OUTMODE == 2 && tid < 64) bsh[tid] = batch[node0 + tid];

    __syncthreads();

    // ---- epilogue: BN/ReLU, stage C (fp16) in As ----
#pragma unroll
    for (int nt = 0; nt < 2; ++nt) {
        int c = wv * 32 + nt * 16 + lm;
        float s = g[c] * rsqrtf(rv[c] + BN_EPS);
        float o = fmaf(b[c] - rm[c], s, bt[c]);
#pragma unroll
        for (int mt = 0; mt < 4; ++mt) {
            float dvr[4] = {dv4[mt].x, dv4[mt].y, dv4[mt].z, dv4[mt].w};
#pragma unroll
            for (int r = 0; r < 4; ++r) {
                float pm = PRE ? dvr[r] : 1.0f;
                float y = fmaxf(fmaf(acc[mt][nt][r] * dvr[r], s, o), 0.f) * pm;
                As[mt * 16 + lq * 4 + r][c] = __float2half_rn(y);
            }
        }
    }
    __syncthreads();

    if (OUTMODE == 1) {
#pragma unroll
        for (int i = 0; i < 2; ++i) {
            int u = tid + i * 256;                 // 0..511
            int row = u >> 3, cb = (u & 7) * 16;   // 16 cols/thread
            float fa[8], fb[8];
            set8(*(const uint4*)(&As[row][cb]), fa);
            set8(*(const uint4*)(&As[row][cb + 8]), fb);
            uint2 pa = pack8_fp8(fa), pb = pack8_fp8(fb);
            uint4 v; v.x = pa.x; v.y = pa.y; v.z = pb.x; v.w = pb.y;
            *(uint4*)(hout8 + (size_t)(node0 + row) * 128 + cb) = v;
        }
    } else {
        // fused segment-sum pooling (batch sorted): run-length sum by graph.
        const int c = tid & 127;
        const int r0 = (tid >> 7) * 32;
        float accp = 0.f;
        int g0 = bsh[r0];
        for (int row = r0; row < r0 + 32; ++row) {
            int gg = bsh[row];
            if (gg != g0) {
                atomicAdd(&g_agg7[(size_t)g0 * 128 + c], accp);
                accp = 0.f; g0 = gg;
            }
            accp += __half2float(As[row][c]);
        }
        atomicAdd(&g_agg7[(size_t)g0 * 128 + c], accp);
    }
}

// ---------------- fused head: hidden in LDS, logits out (1 launch) --------

__global__ __launch_bounds__(256) void k_head(const float* __restrict__ Wc1,
                                              const float* __restrict__ bc1,
                                              const float* __restrict__ Wc2,
                                              const float* __restrict__ bc2,
                                              float* __restrict__ out) {
    __shared__ float hsh[4][64];
    const int g4 = blockIdx.x * 4;              // 4 graphs per block
    const int gi = g4 + (threadIdx.x >> 6);
    const int c = threadIdx.x & 63;
    const float* pooled = g_agg7;
    int cnt = g_gstart[gi + 1] - g_gstart[gi];
    float inv = 1.0f / (float)max(cnt, 1);
    float z = 0.f;
#pragma unroll 8
    for (int k = 0; k < 128; ++k) z = fmaf(pooled[(size_t)gi * 128 + k], Wc1[k * 64 + c], z);
    hsh[threadIdx.x >> 6][c] = fmaxf(fmaf(z, inv, bc1[c]), 0.f);
    __syncthreads();
    if (threadIdx.x < 4) {
        float zz = bc2[0];
#pragma unroll 8
        for (int k = 0; k < 64; ++k) zz = fmaf(hsh[threadIdx.x][k], Wc2[k], zz);
        out[g4 + threadIdx.x] = zz;
    }
}

// ---------------- launch ----------------

extern "C" void kernel_launch(void* const* d_in, const int* in_sizes, int n_in,
                              void* d_out, int out_size, void* d_ws, size_t ws_size,
                              hipStream_t stream) {
    const float* x     = (const float*)d_in[0];
    const int*   ei    = (const int*)d_in[1];
    const int*   batch = (const int*)d_in[2];
    const float* W1 = (const float*)d_in[3];
    const float* b1 = (const float*)d_in[4];
    const float* g1 = (const float*)d_in[5];
    const float* bt1= (const float*)d_in[6];
    const float* rm1= (const float*)d_in[7];
    const float* rv1= (const float*)d_in[8];
    const float* W2 = (const float*)d_in[9];
    const float* b2 = (const float*)d_in[10];
    const float* g2 = (const float*)d_in[11];
    const float* bt2= (const float*)d_in[12];
    const float* rm2= (const float*)d_in[13];
    const float* rv2= (const float*)d_in[14];
    const float* W3 = (const float*)d_in[15];
    const float* b3 = (const float*)d_in[16];
    const float* g3 = (const float*)d_in[17];
    const float* bt3= (const float*)d_in[18];
    const float* rm3= (const float*)d_in[19];
    const float* rv3= (const float*)d_in[20];
    const float* Wc1= (const float*)d_in[21];
    const float* bc1= (const float*)d_in[22];
    const float* Wc2= (const float*)d_in[23];
    const float* bc2= (const float*)d_in[24];
    float* outp = (float*)d_out;
    (void)d_ws; (void)ws_size; (void)n_in; (void)in_sizes;

    const int* srcp = ei;
    const int* dstp = ei + N_EDGES;

    // prep: zero rowcnt/bcnt + wt1/wt2/wt3 transposes (1,037,120 threads)
    k_prep<<<4052, 256, 0, stream>>>(W1, W2, W3);

    // bucketed CSR build (r28): hist -> scan -> bin -> degrees
    k_bhist<<<NSCAT, 256, 0, stream>>>(dstp);
    k_bscan<<<1, 256, 0, stream>>>();
    k_bscatter<<<NSCAT, 256, 0, stream>>>(srcp, dstp);
    k_bdeg<<<NB, 256, 0, stream>>>();

    // row_start scan (scan1 also emits dinv + px fp16x8)
    k_scan1<<<NBLK1, 256, 0, stream>>>(x);
    k_scan2<<<1, 256, 0, stream>>>();
    k_scan3<<<NBLK1, 256, 0, stream>>>();

    // per-bucket csr scatter (L2-local writes)
    k_bcsr<<<NB, 256, 0, stream>>>();

    // graph boundaries + pooled-sum zeroing (1 launch)
    k_gz<<<4225, 256, 0, stream>>>(batch);

    // layer 1: fused gather+MFMA lin1+BN/ReLU -> q1 fp8
    k_l1_fused<<<N_NODES / 64, 256, 0, stream>>>(b1, g1, bt1, rm1, rv1);

    // layers 2,3: fused gather + MFMA GEMM
    k_agg_gemm<true,  true,  0, 1><<<N_NODES / 64, 256, 0, stream>>>(b2, g2, bt2, rm2, rv2, batch);
    k_agg_gemm<false, false, 1, 2><<<N_NODES / 64, 256, 0, stream>>>(b3, g3, bt3, rm3, rv3, batch);

    // fused head MLP
    k_head<<<N_GRAPHS / 4, 256, 0, stream>>>(Wc1, bc1, Wc2, bc2, outp);
}

// Round 12
// 887.871 us; speedup vs baseline: 1.3449x; 1.0250x over previous
//
#include <hip/hip_runtime.h>
#include <hip/hip_fp16.h>

#define N_NODES 1000000
#define N_EDGES 4000000
#define N_GRAPHS 32768
#define BN_EPS 1e-5f
#define NBLK1 3907   // ceil(N_NODES/256)
#define NB 256       // csr-build buckets (dst >> 12)
#define BKT_SHIFT 12
#define EPB 2048     // edges per bucket-scatter block
#define NSCAT 1954   // ceil(N_EDGES / EPB)
#define CAPB 32      // per-block per-bucket LDS list capacity

typedef _Float16 f16;
typedef f16   f16x8 __attribute__((ext_vector_type(8)));
typedef float f32x4 __attribute__((ext_vector_type(4)));
typedef float f32x2 __attribute__((ext_vector_type(2)));

// ---------------------------------------------------------------------------
// Static device-global scratch.
// r21 fp8 gather rows. r22 fused pooling. r23 l1 fused. r25 launch fusion.
// r26/r27 2-list interleaved gather (ERRATA r10: clamp fix did NOT cut
// FETCH — 566 MB is inherent to the interleaved pattern; still net +).
// r28 bucketed CSR build (scatter 209us -> gone from top-5).
// r29: l1 8-wide clamped gather (serial tail deleted); pooled-zero in prep.
// ---------------------------------------------------------------------------
__device__ __half g_hA[128000000];      // 256 MB: q1 fp8 (first 128 MB)
__device__ __half g_hB[128000000];      // 256 MB: px fp16x8 (16 MB) -> h2 fp8 (128 MB)
__device__ float  g_agg7[8400000];      //  33.6 MB: pooled SUMS
__device__ float  g_dinv[N_NODES];
__device__ int    g_rowcnt[N_NODES];
__device__ int    g_row_start[N_NODES + 1];
__device__ int    g_csr_src[N_EDGES];
__device__ unsigned g_pairs[N_EDGES];   // 16 MB packed (src<<12 | dst&4095)
__device__ int    g_part[NBLK1];
__device__ int    g_gstart[N_GRAPHS + 1];
__device__ int    g_bcnt[NB];
__device__ int    g_bstart[NB + 1];
__device__ int    g_bcur[NB];
__device__ __align__(16) __half g_wt1[4096];    // W1^T fp16 [n][k], K padded to 32
__device__ __align__(16) __half g_wt2[16384];   // W2^T fp16 [n][k]
__device__ __align__(16) __half g_wt3[16384];   // W3^T fp16 [n][k]

// ---------------- fp16 helpers ----------------

__device__ __forceinline__ void set8(uint4 raw, float f[8]) {
    __half2 h; float2 a;
    __builtin_memcpy(&h, &raw.x, 4); a = __half22float2(h); f[0] = a.x; f[1] = a.y;
    __builtin_memcpy(&h, &raw.y, 4); a = __half22float2(h); f[2] = a.x; f[3] = a.y;
    __builtin_memcpy(&h, &raw.z, 4); a = __half22float2(h); f[4] = a.x; f[5] = a.y;
    __builtin_memcpy(&h, &raw.w, 4); a = __half22float2(h); f[6] = a.x; f[7] = a.y;
}
__device__ __forceinline__ uint4 pack8(const float f[8]) {
    __half2 h0 = __floats2half2_rn(f[0], f[1]);
    __half2 h1 = __floats2half2_rn(f[2], f[3]);
    __half2 h2 = __floats2half2_rn(f[4], f[5]);
    __half2 h3 = __floats2half2_rn(f[6], f[7]);
    uint4 raw;
    __builtin_memcpy(&raw.x, &h0, 4);
    __builtin_memcpy(&raw.y, &h1, 4);
    __builtin_memcpy(&raw.z, &h2, 4);
    __builtin_memcpy(&raw.w, &h3, 4);
    return raw;
}
__device__ __forceinline__ f32x2 cvt2h(unsigned raw) {
    __half2 h; __builtin_memcpy(&h, &raw, 4);
    float2 a = __half22float2(h);
    f32x2 r; r.x = a.x; r.y = a.y; return r;
}

// ---------------- fp8 e4m3 helpers (vector f32x2 accumulators) ----------------

__device__ __forceinline__ void set8_fp8v(uint2 raw, f32x2 f[4]) {
    f[0] = __builtin_amdgcn_cvt_pk_f32_fp8(raw.x, false);
    f[1] = __builtin_amdgcn_cvt_pk_f32_fp8(raw.x, true);
    f[2] = __builtin_amdgcn_cvt_pk_f32_fp8(raw.y, false);
    f[3] = __builtin_amdgcn_cvt_pk_f32_fp8(raw.y, true);
}
__device__ __forceinline__ void add8_fp8v(uint2 raw, f32x2 f[4]) {
    f[0] += __builtin_amdgcn_cvt_pk_f32_fp8(raw.x, false);   // v_pk_add_f32
    f[1] += __builtin_amdgcn_cvt_pk_f32_fp8(raw.x, true);
    f[2] += __builtin_amdgcn_cvt_pk_f32_fp8(raw.y, false);
    f[3] += __builtin_amdgcn_cvt_pk_f32_fp8(raw.y, true);
}
__device__ __forceinline__ uint4 pack8v(const f32x2 f[4]) {
    __half2 h0 = __floats2half2_rn(f[0].x, f[0].y);
    __half2 h1 = __floats2half2_rn(f[1].x, f[1].y);
    __half2 h2 = __floats2half2_rn(f[2].x, f[2].y);
    __half2 h3 = __floats2half2_rn(f[3].x, f[3].y);
    uint4 raw;
    __builtin_memcpy(&raw.x, &h0, 4);
    __builtin_memcpy(&raw.y, &h1, 4);
    __builtin_memcpy(&raw.z, &h2, 4);
    __builtin_memcpy(&raw.w, &h3, 4);
    return raw;
}
__device__ __forceinline__ uint2 pack8_fp8(const float f[8]) {
    int lo = 0, hi = 0;
    lo = __builtin_amdgcn_cvt_pk_fp8_f32(f[0], f[1], lo, false);
    lo = __builtin_amdgcn_cvt_pk_fp8_f32(f[2], f[3], lo, true);
    hi = __builtin_amdgcn_cvt_pk_fp8_f32(f[4], f[5], hi, false);
    hi = __builtin_amdgcn_cvt_pk_fp8_f32(f[6], f[7], hi, true);
    uint2 r; r.x = (unsigned)lo; r.y = (unsigned)hi; return r;
}

// ---- prep: zero rowcnt/bcnt/pooled + weight transposes (1 launch) ----

__global__ __launch_bounds__(256) void k_prep(const float* __restrict__ W1,
                                              const float* __restrict__ W2,
                                              const float* __restrict__ W3) {
    int t = blockIdx.x * 256 + threadIdx.x;
    if (t < N_NODES) { g_rowcnt[t] = 0; return; }
    int u = t - N_NODES;
    if (u < 32768) {                       // W2/W3 -> fp16 transposed
        int sel = u >> 14, v = u & 16383;
        int n = v & 127, k = v >> 7;
        (sel ? g_wt3 : g_wt2)[n * 128 + k] = __float2half_rn((sel ? W3 : W2)[k * 128 + n]);
        return;
    }
    u -= 32768;
    if (u < 4096) {                        // W1^T fp16 [128][32], k>=7 zero
        int n = u & 127, k = u >> 7;
        g_wt1[n * 32 + k] = (k < 7) ? __float2half_rn(W1[k * 128 + n]) : __float2half_rn(0.f);
        return;
    }
    u -= 4096;
    if (u < NB) { g_bcnt[u] = 0; return; }
    u -= NB;
    if (u < 1048576)                       // zero pooled sums (16.78 MB)
        *(float4*)(g_agg7 + (size_t)u * 4) = make_float4(0.f, 0.f, 0.f, 0.f);
}

// ---------------- bucketed CSR build (r28) ----------------

__global__ __launch_bounds__(256) void k_bhist(const int* __restrict__ dst) {
    __shared__ int h[NB];
    h[threadIdx.x] = 0;
    __syncthreads();
    int base = blockIdx.x * EPB;
#pragma unroll
    for (int k = 0; k < 8; ++k) {
        int e = base + k * 256 + threadIdx.x;
        if (e < N_EDGES) atomicAdd(&h[((unsigned)dst[e]) >> BKT_SHIFT], 1);
    }
    __syncthreads();
    int c = h[threadIdx.x];
    if (c) atomicAdd(&g_bcnt[threadIdx.x], c);
}

__global__ __launch_bounds__(256) void k_bscan() {
    __shared__ int sh[256];
    int v = g_bcnt[threadIdx.x];
    sh[threadIdx.x] = v;
    __syncthreads();
#pragma unroll
    for (int off = 1; off < 256; off <<= 1) {
        int t = (threadIdx.x >= off) ? sh[threadIdx.x - off] : 0;
        __syncthreads();
        sh[threadIdx.x] += t;
        __syncthreads();
    }
    int excl = sh[threadIdx.x] - v;
    g_bstart[threadIdx.x] = excl;
    g_bcur[threadIdx.x] = excl;
    if (threadIdx.x == 255) g_bstart[NB] = N_EDGES;
}

__global__ __launch_bounds__(256) void k_bscatter(const int* __restrict__ src,
                                                  const int* __restrict__ dst) {
    __shared__ int lcnt[NB];
    __shared__ unsigned llist[NB][CAPB];     // 32 KB
    lcnt[threadIdx.x] = 0;
    __syncthreads();
    int base = blockIdx.x * EPB;
#pragma unroll
    for (int k = 0; k < 8; ++k) {
        int e = base + k * 256 + threadIdx.x;
        if (e < N_EDGES) {
            unsigned d = (unsigned)dst[e];
            unsigned p = (((unsigned)src[e]) << BKT_SHIFT) | (d & 4095u);
            int b = (int)(d >> BKT_SHIFT);
            int slot = atomicAdd(&lcnt[b], 1);
            if (slot < CAPB) llist[b][slot] = p;
            else {                               // rare overflow: direct reserve
                int gpos = atomicAdd(&g_bcur[b], 1);
                g_pairs[gpos] = p;
            }
        }
    }
    __syncthreads();
    int c = min(lcnt[threadIdx.x], CAPB);
    if (c > 0) {
        int gbase = atomicAdd(&g_bcur[threadIdx.x], c);
        for (int i = 0; i < c; ++i) g_pairs[gbase + i] = llist[threadIdx.x][i];
    }
}

__global__ __launch_bounds__(256) void k_bdeg() {
    __shared__ int cnt[4096];                // 16 KB
    const int b = blockIdx.x;
    for (int j = threadIdx.x; j < 4096; j += 256) cnt[j] = 0;
    __syncthreads();
    const int s0 = g_bstart[b], s1 = g_bstart[b + 1];
    for (int i = s0 + threadIdx.x; i < s1; i += 256)
        atomicAdd(&cnt[g_pairs[i] & 4095u], 1);
    __syncthreads();
    const int n0 = b << BKT_SHIFT;
    for (int j = threadIdx.x; j < 4096; j += 256)
        if (n0 + j < N_NODES) g_rowcnt[n0 + j] = cnt[j];
}

__global__ __launch_bounds__(256) void k_bcsr() {
    __shared__ int cnt[4096];
    const int b = blockIdx.x;
    for (int j = threadIdx.x; j < 4096; j += 256) cnt[j] = 0;
    __syncthreads();
    const int s0 = g_bstart[b], s1 = g_bstart[b + 1];
    const int n0 = b << BKT_SHIFT;
    for (int i = s0 + threadIdx.x; i < s1; i += 256) {
        unsigned p = g_pairs[i];
        int dl = (int)(p & 4095u);
        int off = atomicAdd(&cnt[dl], 1);
        int pos = g_row_start[n0 + dl] + off;
        g_csr_src[pos] = (int)(p >> BKT_SHIFT);
    }
}

// scan1 also computes dinv AND px (fp16x8 row of dinv*x)
__global__ __launch_bounds__(256) void k_scan1(const float* __restrict__ x) {
    __shared__ int sh[256];
    int i = blockIdx.x * 256 + threadIdx.x;
    int v = (i < N_NODES) ? g_rowcnt[i] : 0;
    if (i < N_NODES) {
        float w = rsqrtf((float)(1 + v));   // +1 self-loop
        g_dinv[i] = w;
        float vv[8];
#pragma unroll
        for (int k = 0; k < 7; ++k) vv[k] = x[i * 7 + k] * w;
        vv[7] = 0.f;
        *(uint4*)(g_hB + (size_t)i * 8) = pack8(vv);
    }
    sh[threadIdx.x] = v;
    __syncthreads();
#pragma unroll
    for (int off = 1; off < 256; off <<= 1) {
        int t = (threadIdx.x >= off) ? sh[threadIdx.x - off] : 0;
        __syncthreads();
        sh[threadIdx.x] += t;
        __syncthreads();
    }
    int incl = sh[threadIdx.x];
    if (i < N_NODES) g_row_start[i] = incl - v;
    if (threadIdx.x == 255) g_part[blockIdx.x] = incl;
}

__global__ __launch_bounds__(256) void k_scan2() {
    __shared__ int sh[256];
    int base = threadIdx.x * 16;
    int local[16];
    int s = 0;
#pragma unroll
    for (int k = 0; k < 16; ++k) {
        local[k] = (base + k < NBLK1) ? g_part[base + k] : 0;
        s += local[k];
    }
    sh[threadIdx.x] = s;
    __syncthreads();
#pragma unroll
    for (int off = 1; off < 256; off <<= 1) {
        int t = (threadIdx.x >= off) ? sh[threadIdx.x - off] : 0;
        __syncthreads();
        sh[threadIdx.x] += t;
        __syncthreads();
    }
    int carry = sh[threadIdx.x] - s;
#pragma unroll
    for (int k = 0; k < 16; ++k) {
        if (base + k < NBLK1) {
            int t = local[k];
            g_part[base + k] = carry;
            carry += t;
        }
    }
}

__global__ __launch_bounds__(256) void k_scan3() {
    int i = blockIdx.x * 256 + threadIdx.x;
    if (i < N_NODES) g_row_start[i] += g_part[blockIdx.x];
    if (i == 0) g_row_start[N_NODES] = N_EDGES;
}

// ---------------- gstart (pooled-zero moved to prep) ----------------

__global__ __launch_bounds__(256) void k_gstart(const int* __restrict__ batch) {
    int gidx = blockIdx.x * 256 + threadIdx.x;
    if (gidx > N_GRAPHS) return;
    int lo = 0, hi = N_NODES;
    while (lo < hi) {
        int mid = (lo + hi) >> 1;
        if (batch[mid] < gidx) lo = mid + 1; else hi = mid;
    }
    g_gstart[gidx] = lo;
}

// ---------------- fused layer-1: gather(px) + MFMA lin1 + BN/ReLU -> q1 fp8
// r29: 8-wide clamped batches (clamp to own last edge; fp16 0x0000 zeros
// for overshoot -> adding +0.0 keeps f32 sums exact; serial tail deleted).

__global__ __launch_bounds__(256, 7) void k_l1_fused(const float* __restrict__ b,
                                                     const float* __restrict__ g,
                                                     const float* __restrict__ bt,
                                                     const float* __restrict__ rm,
                                                     const float* __restrict__ rv) {
    const __half* __restrict__ px = g_hB;
    unsigned char* __restrict__ q1 = (unsigned char*)g_hA;

    __shared__ __half As[64][152];          // 19,456 B
    const int tid = threadIdx.x;
    const int node0 = blockIdx.x * 64;

    // ---- gather: 4 threads/node, one pass, 8-wide clamped batches ----
    {
        const int slot = tid >> 2;          // 0..63
        const int q = tid & 3;              // channel pair
        int i = node0 + slot;
        f32x2 f = cvt2h(*(const unsigned*)(px + (size_t)i * 8 + q * 2));   // self
        const int e0 = g_row_start[i], e1 = g_row_start[i + 1];
        const int em = min(max(e1 - 1, e0), N_EDGES - 1);
        for (int e = e0; e < e1; e += 8) {
            int s0 = g_csr_src[min(e,     em)];
            int s1 = g_csr_src[min(e + 1, em)];
            int s2 = g_csr_src[min(e + 2, em)];
            int s3 = g_csr_src[min(e + 3, em)];
            int s4 = g_csr_src[min(e + 4, em)];
            int s5 = g_csr_src[min(e + 5, em)];
            int s6 = g_csr_src[min(e + 6, em)];
            int s7 = g_csr_src[min(e + 7, em)];
            unsigned r0 = *(const unsigned*)(px + (size_t)s0 * 8 + q * 2);
            unsigned r1 = *(const unsigned*)(px + (size_t)s1 * 8 + q * 2);
            unsigned r2 = *(const unsigned*)(px + (size_t)s2 * 8 + q * 2);
            unsigned r3 = *(const unsigned*)(px + (size_t)s3 * 8 + q * 2);
            unsigned r4 = *(const unsigned*)(px + (size_t)s4 * 8 + q * 2);
            unsigned r5 = *(const unsigned*)(px + (size_t)s5 * 8 + q * 2);
            unsigned r6 = *(const unsigned*)(px + (size_t)s6 * 8 + q * 2);
            unsigned r7 = *(const unsigned*)(px + (size_t)s7 * 8 + q * 2);
            __builtin_amdgcn_sched_barrier(0);   // keep loads clustered
            if (e + 1 >= e1) r1 = 0u;            // fp16 0x0000 == +0.0
            if (e + 2 >= e1) r2 = 0u;
            if (e + 3 >= e1) r3 = 0u;
            if (e + 4 >= e1) r4 = 0u;
            if (e + 5 >= e1) r5 = 0u;
            if (e + 6 >= e1) r6 = 0u;
            if (e + 7 >= e1) r7 = 0u;
            f += cvt2h(r0); f += cvt2h(r1); f += cvt2h(r2); f += cvt2h(r3);
            f += cvt2h(r4); f += cvt2h(r5); f += cvt2h(r6); f += cvt2h(r7);
        }
        __half2 hv = __floats2half2_rn(f.x, f.y);
        unsigned u; __builtin_memcpy(&u, &hv, 4);
        *(unsigned*)(&As[slot][q * 2]) = u;
        uint4 z; z.x = 0; z.y = 0; z.z = 0; z.w = 0;
        *(uint4*)(&As[slot][8 + q * 8]) = z;    // zero K pad halves 8..39
    }

    const int wv = tid >> 6;        // wave 0..3 -> cols [wv*32, wv*32+32)
    const int lane = tid & 63;
    const int lm = lane & 15;
    const int lq = lane >> 4;

    __syncthreads();

    // ---- MFMA: K=32 (single kb) ----
    f32x4 acc[4][2];
#pragma unroll
    for (int mt = 0; mt < 4; ++mt)
#pragma unroll
        for (int nt = 0; nt < 2; ++nt) acc[mt][nt] = (f32x4){0.f, 0.f, 0.f, 0.f};

    f16x8 bq[2];
#pragma unroll
    for (int nt = 0; nt < 2; ++nt)
        __builtin_memcpy(&bq[nt], g_wt1 + (size_t)(wv * 32 + nt * 16 + lm) * 32 + lq * 8, 16);
#pragma unroll
    for (int mt = 0; mt < 4; ++mt) {
        f16x8 afr;
        __builtin_memcpy(&afr, &As[mt * 16 + lm][lq * 8], 16);
#pragma unroll
        for (int nt = 0; nt < 2; ++nt)
            acc[mt][nt] = __builtin_amdgcn_mfma_f32_16x16x32_f16(afr, bq[nt], acc[mt][nt], 0, 0, 0);
    }

    float4 dv4[4];
#pragma unroll
    for (int mt = 0; mt < 4; ++mt)
        dv4[mt] = *(const float4*)(g_dinv + node0 + mt * 16 + lq * 4);

    __syncthreads();   // all As gather reads done before C staging

    // ---- epilogue: BN/ReLU (PRE), stage C fp16 in As ----
#pragma unroll
    for (int nt = 0; nt < 2; ++nt) {
        int c = wv * 32 + nt * 16 + lm;
        float s = g[c] * rsqrtf(rv[c] + BN_EPS);
        float o = fmaf(b[c] - rm[c], s, bt[c]);
#pragma unroll
        for (int mt = 0; mt < 4; ++mt) {
            float dvr[4] = {dv4[mt].x, dv4[mt].y, dv4[mt].z, dv4[mt].w};
#pragma unroll
            for (int r = 0; r < 4; ++r) {
                float y = fmaxf(fmaf(acc[mt][nt][r] * dvr[r], s, o), 0.f) * dvr[r];
                As[mt * 16 + lq * 4 + r][c] = __float2half_rn(y);
            }
        }
    }
    __syncthreads();
#pragma unroll
    for (int i = 0; i < 2; ++i) {
        int u = tid + i * 256;                 // 0..511
        int row = u >> 3, cb = (u & 7) * 16;   // 16 cols/thread
        float fa[8], fb[8];
        set8(*(const uint4*)(&As[row][cb]), fa);
        set8(*(const uint4*)(&As[row][cb + 8]), fb);
        uint2 pa = pack8_fp8(fa), pb = pack8_fp8(fb);
        uint4 v; v.x = pa.x; v.y = pa.y; v.z = pb.x; v.w = pb.y;
        *(uint4*)(q1 + (size_t)(node0 + row) * 128 + cb) = v;
    }
}

// ---------------- fused CSR-gather + MFMA GEMM + BN + ReLU (layers 2,3) ----
// LEDGER:
//  r18 interleave (fp16 era) -> spills. r19 nt stores -> WRITE x5.
//  r19b bounds(256,8) -> thrash. r21 fp8 rows 374->277. r22 fused pooling
//  277->237. r24 degree-sort REGRESSED. r26/r27 2-list interleave 237->216
//  (ERRATA: FETCH 566 MB is pattern-inherent, not the clamp bug).
//  r28 bucketed CSR. Layer-3 now at ~2.85 TB/s L2-fill service equilibrium.
// OUTMODE: 1 = fp8 row store (layer 2), 2 = fused pool (layer 3).

template <bool PRE, bool ATOB, int WSEL, int OUTMODE>
__global__ __launch_bounds__(256, 7) void k_agg_gemm(const float* __restrict__ b,
                                                     const float* __restrict__ g,
                                                     const float* __restrict__ bt,
                                                     const float* __restrict__ rm,
                                                     const float* __restrict__ rv,
                                                     const int* __restrict__ batch) {
    const unsigned char* __restrict__ hin8 =
        (const unsigned char*)(ATOB ? g_hA : g_hB);          // fp8 rows, 128 B
    unsigned char* __restrict__ hout8 =
        (unsigned char*)(ATOB ? g_hB : g_hA);                // fp8 rows, 128 B
    const __half* __restrict__ WtG = (WSEL == 0) ? g_wt2 : g_wt3;

    __shared__ __half As[64][152];          // 19,456 B
    __shared__ int bsh[64];
    const int tid = threadIdx.x;
    const int node0 = blockIdx.x * 64;

    // ---- gather: 2-list interleave, clamped-to-own-last-edge batches ----
    {
        const int slot = tid >> 4;          // 0..15
        const int c0 = (tid & 15) * 8;      // 8 channels = 8 fp8 bytes
#pragma unroll
        for (int pair = 0; pair < 2; ++pair) {
            const int iA = node0 + (pair * 2 + 0) * 16 + slot;
            const int iB = node0 + (pair * 2 + 1) * 16 + slot;
            f32x2 fA[4], fB[4];
            set8_fp8v(*(const uint2*)(hin8 + (size_t)iA * 128 + c0), fA);   // self A
            set8_fp8v(*(const uint2*)(hin8 + (size_t)iB * 128 + c0), fB);   // self B
            const int eA = g_row_start[iA], e1A = g_row_start[iA + 1];
            const int eB = g_row_start[iB], e1B = g_row_start[iB + 1];
            const int emA = min(max(e1A - 1, eA), N_EDGES - 1);
            const int emB = min(max(e1B - 1, eB), N_EDGES - 1);
            const int dmax = max(e1A - eA, e1B - eB);
            for (int done = 0; done < dmax; done += 4) {
                const int bA = eA + done, bB = eB + done;
                int sA0 = g_csr_src[min(bA,     emA)];
                int sA1 = g_csr_src[min(bA + 1, emA)];
                int sA2 = g_csr_src[min(bA + 2, emA)];
                int sA3 = g_csr_src[min(bA + 3, emA)];
                int sB0 = g_csr_src[min(bB,     emB)];
                int sB1 = g_csr_src[min(bB + 1, emB)];
                int sB2 = g_csr_src[min(bB + 2, emB)];
                int sB3 = g_csr_src[min(bB + 3, emB)];
                uint2 rA0 = *(const uint2*)(hin8 + (size_t)sA0 * 128 + c0);
                uint2 rA1 = *(const uint2*)(hin8 + (size_t)sA1 * 128 + c0);
                uint2 rA2 = *(const uint2*)(hin8 + (size_t)sA2 * 128 + c0);
                uint2 rA3 = *(const uint2*)(hin8 + (size_t)sA3 * 128 + c0);
                uint2 rB0 = *(const uint2*)(hin8 + (size_t)sB0 * 128 + c0);
                uint2 rB1 = *(const uint2*)(hin8 + (size_t)sB1 * 128 + c0);
                uint2 rB2 = *(const uint2*)(hin8 + (size_t)sB2 * 128 + c0);
                uint2 rB3 = *(const uint2*)(hin8 + (size_t)sB3 * 128 + c0);
                __builtin_amdgcn_sched_barrier(0);   // keep the 8 row loads clustered
                if (bA     >= e1A) { rA0.x = 0u; rA0.y = 0u; }   // fp8 0x00 == 0.0
                if (bA + 1 >= e1A) { rA1.x = 0u; rA1.y = 0u; }
                if (bA + 2 >= e1A) { rA2.x = 0u; rA2.y = 0u; }
                if (bA + 3 >= e1A) { rA3.x = 0u; rA3.y = 0u; }
                if (bB     >= e1B) { rB0.x = 0u; rB0.y = 0u; }
                if (bB + 1 >= e1B) { rB1.x = 0u; rB1.y = 0u; }
                if (bB + 2 >= e1B) { rB2.x = 0u; rB2.y = 0u; }
                if (bB + 3 >= e1B) { rB3.x = 0u; rB3.y = 0u; }
                add8_fp8v(rA0, fA); add8_fp8v(rA1, fA); add8_fp8v(rA2, fA); add8_fp8v(rA3, fA);
                add8_fp8v(rB0, fB); add8_fp8v(rB1, fB); add8_fp8v(rB2, fB); add8_fp8v(rB3, fB);
            }
            *(uint4*)(&As[(pair * 2 + 0) * 16 + slot][c0]) = pack8v(fA);
            *(uint4*)(&As[(pair * 2 + 1) * 16 + slot][c0]) = pack8v(fB);
        }
    }

    const int wv = tid >> 6;        // wave 0..3 -> cols [wv*32, wv*32+32)
    const int lane = tid & 63;
    const int lm = lane & 15;
    const int lq = lane >> 4;

    __syncthreads();

    // ---- MFMA: kb-outer so only 2 B-frags live at a time ----
    f32x4 acc[4][2];
#pragma unroll
    for (int mt = 0; mt < 4; ++mt)
#pragma unroll
        for (int nt = 0; nt < 2; ++nt) acc[mt][nt] = (f32x4){0.f, 0.f, 0.f, 0.f};

#pragma unroll
    for (int kb = 0; kb < 4; ++kb) {
        f16x8 bq[2];
#pragma unroll
        for (int nt = 0; nt < 2; ++nt)
            __builtin_memcpy(&bq[nt],
                             WtG + (size_t)(wv * 32 + nt * 16 + lm) * 128 + kb * 32 + lq * 8, 16);
#pragma unroll
        for (int mt = 0; mt < 4; ++mt) {
            f16x8 afr;
            __builtin_memcpy(&afr, &As[mt * 16 + lm][kb * 32 + lq * 8], 16);
#pragma unroll
            for (int nt = 0; nt < 2; ++nt)
                acc[mt][nt] = __builtin_amdgcn_mfma_f32_16x16x32_f16(afr, bq[nt], acc[mt][nt], 0, 0, 0);
        }
    }

    float4 dv4[4];
#pragma unroll
    for (int mt = 0; mt < 4; ++mt)
        dv4[mt] = *(const float4*)(g_dinv + node0 + mt * 16 + lq * 4);

    if (OUTMODE == 2 && tid < 64) bsh[tid] = batch[node0 + tid];

    __syncthreads();

    // ---- epilogue: BN/ReLU, stage C (fp16) in As ----
#pragma unroll
    for (int nt = 0; nt < 2; ++nt) {
        int c = wv * 32 + nt * 16 + lm;
        float s = g[c] * rsqrtf(rv[c] + BN_EPS);
        float o = fmaf(b[c] - rm[c], s, bt[c]);
#pragma unroll
        for (int mt = 0; mt < 4; ++mt) {
            float dvr[4] = {dv4[mt].x, dv4[mt].y, dv4[mt].z, dv4[mt].w};
#pragma unroll
            for (int r = 0; r < 4; ++r) {
                float pm = PRE ? dvr[r] : 1.0f;
                float y = fmaxf(fmaf(acc[mt][nt][r] * dvr[r], s, o), 0.f) * pm;
                As[mt * 16 + lq * 4 + r][c] = __float2half_rn(y);
            }
        }
    }
    __syncthreads();

    if (OUTMODE == 1) {
#pragma unroll
        for (int i = 0; i < 2; ++i) {
            int u = tid + i * 256;                 // 0..511
            int row = u >> 3, cb = (u & 7) * 16;   // 16 cols/thread
            float fa[8], fb[8];
            set8(*(const uint4*)(&As[row][cb]), fa);
            set8(*(const uint4*)(&As[row][cb + 8]), fb);
            uint2 pa = pack8_fp8(fa), pb = pack8_fp8(fb);
            uint4 v; v.x = pa.x; v.y = pa.y; v.z = pb.x; v.w = pb.y;
            *(uint4*)(hout8 + (size_t)(node0 + row) * 128 + cb) = v;
        }
    } else {
        // fused segment-sum pooling (batch sorted): run-length sum by graph.
        const int c = tid & 127;
        const int r0 = (tid >> 7) * 32;
        float accp = 0.f;
        int g0 = bsh[r0];
        for (int row = r0; row < r0 + 32; ++row) {
            int gg = bsh[row];
            if (gg != g0) {
                atomicAdd(&g_agg7[(size_t)g0 * 128 + c], accp);
                accp = 0.f; g0 = gg;
            }
            accp += __half2float(As[row][c]);
        }
        atomicAdd(&g_agg7[(size_t)g0 * 128 + c], accp);
    }
}

// ---------------- fused head: hidden in LDS, logits out (1 launch) --------

__global__ __launch_bounds__(256) void k_head(const float* __restrict__ Wc1,
                                              const float* __restrict__ bc1,
                                              const float* __restrict__ Wc2,
                                              const float* __restrict__ bc2,
                                              float* __restrict__ out) {
    __shared__ float hsh[4][64];
    const int g4 = blockIdx.x * 4;              // 4 graphs per block
    const int gi = g4 + (threadIdx.x >> 6);
    const int c = threadIdx.x & 63;
    const float* pooled = g_agg7;
    int cnt = g_gstart[gi + 1] - g_gstart[gi];
    float inv = 1.0f / (float)max(cnt, 1);
    float z = 0.f;
#pragma unroll 8
    for (int k = 0; k < 128; ++k) z = fmaf(pooled[(size_t)gi * 128 + k], Wc1[k * 64 + c], z);
    hsh[threadIdx.x >> 6][c] = fmaxf(fmaf(z, inv, bc1[c]), 0.f);
    __syncthreads();
    if (threadIdx.x < 4) {
        float zz = bc2[0];
#pragma unroll 8
        for (int k = 0; k < 64; ++k) zz = fmaf(hsh[threadIdx.x][k], Wc2[k], zz);
        out[g4 + threadIdx.x] = zz;
    }
}

// ---------------- launch ----------------

extern "C" void kernel_launch(void* const* d_in, const int* in_sizes, int n_in,
                              void* d_out, int out_size, void* d_ws, size_t ws_size,
                              hipStream_t stream) {
    const float* x     = (const float*)d_in[0];
    const int*   ei    = (const int*)d_in[1];
    const int*   batch = (const int*)d_in[2];
    const float* W1 = (const float*)d_in[3];
    const float* b1 = (const float*)d_in[4];
    const float* g1 = (const float*)d_in[5];
    const float* bt1= (const float*)d_in[6];
    const float* rm1= (const float*)d_in[7];
    const float* rv1= (const float*)d_in[8];
    const float* W2 = (const float*)d_in[9];
    const float* b2 = (const float*)d_in[10];
    const float* g2 = (const float*)d_in[11];
    const float* bt2= (const float*)d_in[12];
    const float* rm2= (const float*)d_in[13];
    const float* rv2= (const float*)d_in[14];
    const float* W3 = (const float*)d_in[15];
    const float* b3 = (const float*)d_in[16];
    const float* g3 = (const float*)d_in[17];
    const float* bt3= (const float*)d_in[18];
    const float* rm3= (const float*)d_in[19];
    const float* rv3= (const float*)d_in[20];
    const float* Wc1= (const float*)d_in[21];
    const float* bc1= (const float*)d_in[22];
    const float* Wc2= (const float*)d_in[23];
    const float* bc2= (const float*)d_in[24];
    float* outp = (float*)d_out;
    (void)d_ws; (void)ws_size; (void)n_in; (void)in_sizes;

    const int* srcp = ei;
    const int* dstp = ei + N_EDGES;

    // prep: zero rowcnt/bcnt/pooled + wt transposes (2,085,696 threads)
    k_prep<<<8148, 256, 0, stream>>>(W1, W2, W3);

    // bucketed CSR build: hist -> scan -> bin -> degrees
    k_bhist<<<NSCAT, 256, 0, stream>>>(dstp);
    k_bscan<<<1, 256, 0, stream>>>();
    k_bscatter<<<NSCAT, 256, 0, stream>>>(srcp, dstp);
    k_bdeg<<<NB, 256, 0, stream>>>();

    // row_start scan (scan1 also emits dinv + px fp16x8)
    k_scan1<<<NBLK1, 256, 0, stream>>>(x);
    k_scan2<<<1, 256, 0, stream>>>();
    k_scan3<<<NBLK1, 256, 0, stream>>>();

    // per-bucket csr scatter (L2-local writes)
    k_bcsr<<<NB, 256, 0, stream>>>();

    // graph boundaries
    k_gstart<<<129, 256, 0, stream>>>(batch);

    // layer 1: fused gather+MFMA lin1+BN/ReLU -> q1 fp8
    k_l1_fused<<<N_NODES / 64, 256, 0, stream>>>(b1, g1, bt1, rm1, rv1);

    // layers 2,3: fused gather + MFMA GEMM
    k_agg_gemm<true,  true,  0, 1><<<N_NODES / 64, 256, 0, stream>>>(b2, g2, bt2, rm2, rv2, batch);
    k_agg_gemm<false, false, 1, 2><<<N_NODES / 64, 256, 0, stream>>>(b3, g3, bt3, rm3, rv3, batch);

    // fused head MLP
    k_head<<<N_GRAPHS / 4, 256, 0, stream>>>(Wc1, bc1, Wc2, bc2, outp);
}